// Round 1
// baseline (856.868 us; speedup 1.0000x reference)
//
#include <hip/hip_runtime.h>
#include <hip/hip_bf16.h>

#define H_DIM 128

// ---------------- degree / dinv ----------------
__global__ void degree_kernel(const int* __restrict__ dst, int* __restrict__ deg, int E_) {
    int i = blockIdx.x * blockDim.x + threadIdx.x;
    if (i < E_) atomicAdd(&deg[dst[i]], 1);
}

__global__ void dinv_kernel(const int* __restrict__ deg, float* __restrict__ dinv, int N_) {
    int i = blockIdx.x * blockDim.x + threadIdx.x;
    if (i < N_) dinv[i] = rsqrtf((float)deg[i] + 1.0f);
}

// ---------------- exclusive scan (3-kernel) ----------------
__global__ void scan_block_kernel(const int* __restrict__ deg, int* __restrict__ rowptr,
                                  int* __restrict__ bsum, int N_) {
    __shared__ int sh[256];
    int i = blockIdx.x * 256 + threadIdx.x;
    int v = (i < N_) ? deg[i] : 0;
    sh[threadIdx.x] = v;
    __syncthreads();
    for (int off = 1; off < 256; off <<= 1) {
        int t = (threadIdx.x >= off) ? sh[threadIdx.x - off] : 0;
        __syncthreads();
        sh[threadIdx.x] += t;
        __syncthreads();
    }
    if (i < N_) rowptr[i] = sh[threadIdx.x] - v;   // exclusive
    if (threadIdx.x == 255) bsum[blockIdx.x] = sh[255];
}

__global__ void scan_bsums_kernel(const int* __restrict__ bsum, int* __restrict__ boff, int nb) {
    __shared__ int sh[512];
    int v = (threadIdx.x < nb) ? bsum[threadIdx.x] : 0;
    sh[threadIdx.x] = v;
    __syncthreads();
    for (int off = 1; off < 512; off <<= 1) {
        int t = (threadIdx.x >= off) ? sh[threadIdx.x - off] : 0;
        __syncthreads();
        sh[threadIdx.x] += t;
        __syncthreads();
    }
    if (threadIdx.x < nb) boff[threadIdx.x] = sh[threadIdx.x] - v;  // exclusive
}

__global__ void scan_add_kernel(int* __restrict__ rowptr, const int* __restrict__ boff,
                                int N_, int E_) {
    int i = blockIdx.x * 256 + threadIdx.x;
    if (i < N_) rowptr[i] += boff[blockIdx.x];
    if (i == 0) rowptr[N_] = E_;
}

// ---------------- CSR fill ----------------
__global__ void csr_fill_kernel(const int* __restrict__ src, const int* __restrict__ dst,
                                const int* __restrict__ rowptr, int* __restrict__ cursor,
                                const float* __restrict__ dinv,
                                int* __restrict__ col, float* __restrict__ coef, int E_) {
    int i = blockIdx.x * blockDim.x + threadIdx.x;
    if (i < E_) {
        int d = dst[i], s = src[i];
        int p = rowptr[d] + atomicAdd(&cursor[d], 1);
        col[p] = s;
        coef[p] = dinv[s] * dinv[d];
    }
}

// ---------------- GEMM: Y[N,ldY] = bnrelu(X)[N,128] @ W[128,WCOLS] (+bias) ----------------
// NC = padded col count (multiple of 64 here), MT = 32 nodes/tile, block = 2*NC threads.
template<int NC, bool BN>
__global__ __launch_bounds__(2 * NC) void gemm_kernel(
    const float* __restrict__ X, const float* __restrict__ W,
    const float* __restrict__ Abn, const float* __restrict__ Bbn,
    const float* __restrict__ bias,
    float* __restrict__ Y, int N_, int WCOLS, int ldY)
{
    constexpr int MT = 32;
    constexpr int BLOCK = 2 * NC;
    constexpr int CHUNK = 4096 / BLOCK;        // floats staged per thread
    __shared__ __align__(16) float XT[H_DIM][MT + 4];  // stride 36 floats = 144B (16B-aligned)

    const int t = threadIdx.x;
    const int n0 = blockIdx.x * MT;

    // ---- stage X tile, transposed, with optional fused BN+ReLU ----
    {
        const int n = t & 31;
        const int kbase = (t >> 5) * CHUNK;
        int row = n0 + n;
        if (row >= N_) row = N_ - 1;           // clamp (values unused at store)
        const float* xr = X + (size_t)row * H_DIM;
#pragma unroll
        for (int jj = 0; jj < CHUNK / 4; ++jj) {
            int k = kbase + jj * 4;
            float4 v = *(const float4*)(xr + k);
            if constexpr (BN) {
                float4 a = *(const float4*)(Abn + k);
                float4 b = *(const float4*)(Bbn + k);
                v.x = fmaxf(fmaf(v.x, a.x, b.x), 0.f);
                v.y = fmaxf(fmaf(v.y, a.y, b.y), 0.f);
                v.z = fmaxf(fmaf(v.z, a.z, b.z), 0.f);
                v.w = fmaxf(fmaf(v.w, a.w, b.w), 0.f);
            }
            XT[k + 0][n] = v.x;
            XT[k + 1][n] = v.y;
            XT[k + 2][n] = v.z;
            XT[k + 3][n] = v.w;
        }
    }
    __syncthreads();

    // ---- compute: thread = 4 nodes x 4 cols ----
    const int cg = t >> 3;        // col group 0..NC/4-1
    const int m  = t & 7;         // node group 0..7
    const bool active = (4 * cg) < WCOLS;
    if (active) {
        float acc[4][4];
#pragma unroll
        for (int i = 0; i < 4; ++i)
#pragma unroll
            for (int j = 0; j < 4; ++j) acc[i][j] = 0.f;

        const float* Wp = W + 4 * cg;
#pragma unroll 4
        for (int k = 0; k < H_DIM; ++k) {
            float4 xv = *(const float4*)&XT[k][4 * m];
            float4 wv = *(const float4*)(Wp + (size_t)k * WCOLS);
            acc[0][0] = fmaf(xv.x, wv.x, acc[0][0]);
            acc[0][1] = fmaf(xv.x, wv.y, acc[0][1]);
            acc[0][2] = fmaf(xv.x, wv.z, acc[0][2]);
            acc[0][3] = fmaf(xv.x, wv.w, acc[0][3]);
            acc[1][0] = fmaf(xv.y, wv.x, acc[1][0]);
            acc[1][1] = fmaf(xv.y, wv.y, acc[1][1]);
            acc[1][2] = fmaf(xv.y, wv.z, acc[1][2]);
            acc[1][3] = fmaf(xv.y, wv.w, acc[1][3]);
            acc[2][0] = fmaf(xv.z, wv.x, acc[2][0]);
            acc[2][1] = fmaf(xv.z, wv.y, acc[2][1]);
            acc[2][2] = fmaf(xv.z, wv.z, acc[2][2]);
            acc[2][3] = fmaf(xv.z, wv.w, acc[2][3]);
            acc[3][0] = fmaf(xv.w, wv.x, acc[3][0]);
            acc[3][1] = fmaf(xv.w, wv.y, acc[3][1]);
            acc[3][2] = fmaf(xv.w, wv.z, acc[3][2]);
            acc[3][3] = fmaf(xv.w, wv.w, acc[3][3]);
        }

        float4 bv = make_float4(0.f, 0.f, 0.f, 0.f);
        if (bias) {
            bv.x = bias[4 * cg + 0]; bv.y = bias[4 * cg + 1];
            bv.z = bias[4 * cg + 2]; bv.w = bias[4 * cg + 3];
        }
#pragma unroll
        for (int i = 0; i < 4; ++i) {
            int row = n0 + 4 * m + i;
            if (row < N_) {
                float4 o;
                o.x = acc[i][0] + bv.x;
                o.y = acc[i][1] + bv.y;
                o.z = acc[i][2] + bv.z;
                o.w = acc[i][3] + bv.w;
                *(float4*)(Y + (size_t)row * ldY + 4 * cg) = o;
            }
        }
    }
}

// ---------------- aggregation: out[d] = sum coef_e * H[src_e] + dinv[d]^2 * H[d] + bias ----------------
// one wave per node, float2 per lane
__global__ __launch_bounds__(256) void aggregate_kernel(
    const float* __restrict__ H, const int* __restrict__ rowptr,
    const int* __restrict__ col, const float* __restrict__ coef,
    const float* __restrict__ dinv, const float* __restrict__ bias,
    float* __restrict__ out, int N_)
{
    int wave = threadIdx.x >> 6;
    int lane = threadIdx.x & 63;
    int n = blockIdx.x * 4 + wave;
    if (n >= N_) return;

    const float2* Hp = (const float2*)H;
    float di = dinv[n];
    float2 self = Hp[(size_t)n * 64 + lane];
    float a0 = di * di * self.x;
    float a1 = di * di * self.y;
    float b0 = 0.f, b1 = 0.f;

    int e = rowptr[n];
    int e1 = rowptr[n + 1];
    for (; e + 1 < e1; e += 2) {
        int s0 = col[e], s1 = col[e + 1];
        float c0 = coef[e], c1 = coef[e + 1];
        float2 h0 = Hp[(size_t)s0 * 64 + lane];
        float2 h1 = Hp[(size_t)s1 * 64 + lane];
        a0 = fmaf(c0, h0.x, a0); a1 = fmaf(c0, h0.y, a1);
        b0 = fmaf(c1, h1.x, b0); b1 = fmaf(c1, h1.y, b1);
    }
    if (e < e1) {
        int s = col[e];
        float cf = coef[e];
        float2 h = Hp[(size_t)s * 64 + lane];
        a0 = fmaf(cf, h.x, a0); a1 = fmaf(cf, h.y, a1);
    }
    int c = lane * 2;
    out[(size_t)n * H_DIM + c]     = a0 + b0 + bias[c];
    out[(size_t)n * H_DIM + c + 1] = a1 + b1 + bias[c + 1];
}

// ---------------- BN stats ----------------
__global__ __launch_bounds__(128) void bn_stats_kernel(
    const float* __restrict__ X, float* __restrict__ sum, float* __restrict__ sumsq, int N_)
{
    int c = threadIdx.x;  // 128
    float s = 0.f, s2 = 0.f;
    for (int n = blockIdx.x; n < N_; n += gridDim.x) {
        float v = X[(size_t)n * H_DIM + c];
        s += v;
        s2 = fmaf(v, v, s2);
    }
    atomicAdd(&sum[c], s);
    atomicAdd(&sumsq[c], s2);
}

__global__ __launch_bounds__(128) void bn_finalize_kernel(
    const float* __restrict__ sum, const float* __restrict__ sumsq,
    const float* __restrict__ gamma, const float* __restrict__ beta,
    float* __restrict__ A, float* __restrict__ B, int N_)
{
    int c = threadIdx.x;
    float inv_n = 1.0f / (float)N_;
    float mean = sum[c] * inv_n;
    float var = sumsq[c] * inv_n - mean * mean;
    float rstd = rsqrtf(var + 1e-5f);
    float a = rstd * gamma[c];
    A[c] = a;
    B[c] = beta[c] - mean * a;
}

// ---------------- launch ----------------
extern "C" void kernel_launch(void* const* d_in, const int* in_sizes, int n_in,
                              void* d_out, int out_size, void* d_ws, size_t ws_size,
                              hipStream_t stream) {
    const float* x   = (const float*)d_in[0];
    const int* esrc  = (const int*)d_in[1];
    const int* edst  = (const int*)d_in[2];
    const float* W1  = (const float*)d_in[3];
    const float* b1  = (const float*)d_in[4];
    const float* g1  = (const float*)d_in[5];
    const float* bt1 = (const float*)d_in[6];
    const float* W2  = (const float*)d_in[7];
    const float* b2  = (const float*)d_in[8];
    const float* g2  = (const float*)d_in[9];
    const float* bt2 = (const float*)d_in[10];
    const float* Wr  = (const float*)d_in[11];
    const float* br  = (const float*)d_in[12];

    const int N_ = in_sizes[0] / H_DIM;     // 100000
    const int E_ = in_sizes[1];             // 1600000
    const int OUTC = out_size / N_;         // 40

    // workspace carve (256B aligned)
    char* p = (char*)d_ws;
    auto alloc = [&](size_t bytes) -> void* {
        void* r = (void*)p;
        p += (bytes + 255) & ~(size_t)255;
        return r;
    };
    float* tmpA  = (float*)alloc((size_t)N_ * H_DIM * 4);
    float* tmpB  = (float*)alloc((size_t)N_ * H_DIM * 4);
    int*   col   = (int*)  alloc((size_t)E_ * 4);
    float* coef  = (float*)alloc((size_t)E_ * 4);
    int*   rowptr= (int*)  alloc((size_t)(N_ + 1) * 4);
    int*   degcur= (int*)  alloc((size_t)2 * N_ * 4);  // deg | cursor (zeroed together)
    int*   deg   = degcur;
    int*   cursor= degcur + N_;
    float* dinv  = (float*)alloc((size_t)N_ * 4);
    int*   bsum  = (int*)  alloc(4096);
    int*   boff  = (int*)  alloc(4096);
    float* bnbuf = (float*)alloc(8 * 128 * 4);
    float* sum1 = bnbuf,       *sq1 = bnbuf + 128;
    float* sum2 = bnbuf + 256, *sq2 = bnbuf + 384;
    float* A1 = bnbuf + 512, *B1 = bnbuf + 640;
    float* A2 = bnbuf + 768, *B2 = bnbuf + 896;

    hipMemsetAsync(degcur, 0, (size_t)2 * N_ * 4, stream);
    hipMemsetAsync(bnbuf, 0, 4 * 128 * 4, stream);

    const int nb = (N_ + 255) / 256;
    const int eb = (E_ + 255) / 256;
    const int ntiles = (N_ + 31) / 32;

    degree_kernel<<<eb, 256, 0, stream>>>(edst, deg, E_);
    dinv_kernel<<<nb, 256, 0, stream>>>(deg, dinv, N_);
    scan_block_kernel<<<nb, 256, 0, stream>>>(deg, rowptr, bsum, N_);
    scan_bsums_kernel<<<1, 512, 0, stream>>>(bsum, boff, nb);
    scan_add_kernel<<<nb, 256, 0, stream>>>(rowptr, boff, N_, E_);
    csr_fill_kernel<<<eb, 256, 0, stream>>>(esrc, edst, rowptr, cursor, dinv, col, coef, E_);

    // layer 1
    gemm_kernel<128, false><<<ntiles, 256, 0, stream>>>(x, W1, nullptr, nullptr, nullptr,
                                                        tmpA, N_, H_DIM, H_DIM);
    aggregate_kernel<<<(N_ + 3) / 4, 256, 0, stream>>>(tmpA, rowptr, col, coef, dinv, b1, tmpB, N_);
    bn_stats_kernel<<<512, 128, 0, stream>>>(tmpB, sum1, sq1, N_);
    bn_finalize_kernel<<<1, 128, 0, stream>>>(sum1, sq1, g1, bt1, A1, B1, N_);

    // layer 2 (BN+ReLU fused into GEMM input staging)
    gemm_kernel<128, true><<<ntiles, 256, 0, stream>>>(tmpB, W2, A1, B1, nullptr,
                                                       tmpA, N_, H_DIM, H_DIM);
    aggregate_kernel<<<(N_ + 3) / 4, 256, 0, stream>>>(tmpA, rowptr, col, coef, dinv, b2, tmpB, N_);
    bn_stats_kernel<<<512, 128, 0, stream>>>(tmpB, sum2, sq2, N_);
    bn_finalize_kernel<<<1, 128, 0, stream>>>(sum2, sq2, g2, bt2, A2, B2, N_);

    // readout (BN+ReLU fused, br fused into store)
    gemm_kernel<64, true><<<ntiles, 128, 0, stream>>>(tmpB, Wr, A2, B2, br,
                                                      (float*)d_out, N_, OUTC, OUTC);
}

// Round 2
// 689.233 us; speedup vs baseline: 1.2432x; 1.2432x over previous
//
#include <hip/hip_runtime.h>
#include <hip/hip_bf16.h>
#include <hip/hip_fp16.h>

#define H_DIM 128

// ---------------- degree / dinv ----------------
__global__ void degree_kernel(const int* __restrict__ dst, int* __restrict__ deg, int E_) {
    int i = blockIdx.x * blockDim.x + threadIdx.x;
    if (i < E_) atomicAdd(&deg[dst[i]], 1);
}

__global__ void dinv_kernel(const int* __restrict__ deg, float* __restrict__ dinv, int N_) {
    int i = blockIdx.x * blockDim.x + threadIdx.x;
    if (i < N_) dinv[i] = rsqrtf((float)deg[i] + 1.0f);
}

// ---------------- exclusive scan (3-kernel) ----------------
__global__ void scan_block_kernel(const int* __restrict__ deg, int* __restrict__ rowptr,
                                  int* __restrict__ bsum, int N_) {
    __shared__ int sh[256];
    int i = blockIdx.x * 256 + threadIdx.x;
    int v = (i < N_) ? deg[i] : 0;
    sh[threadIdx.x] = v;
    __syncthreads();
    for (int off = 1; off < 256; off <<= 1) {
        int t = (threadIdx.x >= off) ? sh[threadIdx.x - off] : 0;
        __syncthreads();
        sh[threadIdx.x] += t;
        __syncthreads();
    }
    if (i < N_) rowptr[i] = sh[threadIdx.x] - v;   // exclusive
    if (threadIdx.x == 255) bsum[blockIdx.x] = sh[255];
}

__global__ void scan_bsums_kernel(const int* __restrict__ bsum, int* __restrict__ boff, int nb) {
    __shared__ int sh[512];
    int v = (threadIdx.x < nb) ? bsum[threadIdx.x] : 0;
    sh[threadIdx.x] = v;
    __syncthreads();
    for (int off = 1; off < 512; off <<= 1) {
        int t = (threadIdx.x >= off) ? sh[threadIdx.x - off] : 0;
        __syncthreads();
        sh[threadIdx.x] += t;
        __syncthreads();
    }
    if (threadIdx.x < nb) boff[threadIdx.x] = sh[threadIdx.x] - v;  // exclusive
}

__global__ void scan_add_kernel(int* __restrict__ rowptr, const int* __restrict__ boff,
                                int N_, int E_) {
    int i = blockIdx.x * 256 + threadIdx.x;
    if (i < N_) rowptr[i] += boff[blockIdx.x];
    if (i == 0) rowptr[N_] = E_;
}

// ---------------- CSR fill (packed col+coef) ----------------
__global__ void csr_fill_kernel(const int* __restrict__ src, const int* __restrict__ dst,
                                const int* __restrict__ rowptr, int* __restrict__ cursor,
                                const float* __restrict__ dinv,
                                int2* __restrict__ edges, int E_) {
    int i = blockIdx.x * blockDim.x + threadIdx.x;
    if (i < E_) {
        int d = dst[i], s = src[i];
        int p = rowptr[d] + atomicAdd(&cursor[d], 1);
        edges[p] = make_int2(s, __float_as_int(dinv[s] * dinv[d]));
    }
}

// ---------------- vec helpers ----------------
__device__ inline float4 ld4(const float* p) { return *(const float4*)p; }
__device__ inline float4 ld4(const __half* p) {
    const __half2* q = (const __half2*)p;
    float2 a = __half22float2(q[0]);
    float2 b = __half22float2(q[1]);
    return make_float4(a.x, a.y, b.x, b.y);
}
__device__ inline void st4(float* p, float4 v) { *(float4*)p = v; }
__device__ inline void st4(__half* p, float4 v) {
    ((__half2*)p)[0] = __floats2half2_rn(v.x, v.y);
    ((__half2*)p)[1] = __floats2half2_rn(v.z, v.w);
}

// ---------------- GEMM: Y[N,ldY] = bnrelu(X)[N,128] @ W[128,WCOLS] (+bias) ----------------
template<int NC, bool BN, typename InT, typename OutT>
__global__ __launch_bounds__(2 * NC) void gemm_kernel(
    const InT* __restrict__ X, const float* __restrict__ W,
    const float* __restrict__ Abn, const float* __restrict__ Bbn,
    const float* __restrict__ bias,
    OutT* __restrict__ Y, int N_, int WCOLS, int ldY)
{
    constexpr int MT = 32;
    constexpr int BLOCK = 2 * NC;
    constexpr int CHUNK = 4096 / BLOCK;        // floats staged per thread
    __shared__ __align__(16) float XT[H_DIM][MT + 4];  // stride 36 floats = 144B (16B-aligned)

    const int t = threadIdx.x;
    const int n0 = blockIdx.x * MT;

    // ---- stage X tile, transposed, with optional fused BN+ReLU ----
    {
        const int n = t & 31;
        const int kbase = (t >> 5) * CHUNK;
        int row = n0 + n;
        if (row >= N_) row = N_ - 1;           // clamp (values unused at store)
        const InT* xr = X + (size_t)row * H_DIM;
#pragma unroll
        for (int jj = 0; jj < CHUNK / 4; ++jj) {
            int k = kbase + jj * 4;
            float4 v = ld4(xr + k);
            if constexpr (BN) {
                float4 a = *(const float4*)(Abn + k);
                float4 b = *(const float4*)(Bbn + k);
                v.x = fmaxf(fmaf(v.x, a.x, b.x), 0.f);
                v.y = fmaxf(fmaf(v.y, a.y, b.y), 0.f);
                v.z = fmaxf(fmaf(v.z, a.z, b.z), 0.f);
                v.w = fmaxf(fmaf(v.w, a.w, b.w), 0.f);
            }
            XT[k + 0][n] = v.x;
            XT[k + 1][n] = v.y;
            XT[k + 2][n] = v.z;
            XT[k + 3][n] = v.w;
        }
    }
    __syncthreads();

    // ---- compute: thread = 4 nodes x 4 cols ----
    const int cg = t >> 3;        // col group 0..NC/4-1
    const int m  = t & 7;         // node group 0..7
    const bool active = (4 * cg) < WCOLS;
    if (active) {
        float acc[4][4];
#pragma unroll
        for (int i = 0; i < 4; ++i)
#pragma unroll
            for (int j = 0; j < 4; ++j) acc[i][j] = 0.f;

        const float* Wp = W + 4 * cg;
#pragma unroll 4
        for (int k = 0; k < H_DIM; ++k) {
            float4 xv = *(const float4*)&XT[k][4 * m];
            float4 wv = *(const float4*)(Wp + (size_t)k * WCOLS);
            acc[0][0] = fmaf(xv.x, wv.x, acc[0][0]);
            acc[0][1] = fmaf(xv.x, wv.y, acc[0][1]);
            acc[0][2] = fmaf(xv.x, wv.z, acc[0][2]);
            acc[0][3] = fmaf(xv.x, wv.w, acc[0][3]);
            acc[1][0] = fmaf(xv.y, wv.x, acc[1][0]);
            acc[1][1] = fmaf(xv.y, wv.y, acc[1][1]);
            acc[1][2] = fmaf(xv.y, wv.z, acc[1][2]);
            acc[1][3] = fmaf(xv.y, wv.w, acc[1][3]);
            acc[2][0] = fmaf(xv.z, wv.x, acc[2][0]);
            acc[2][1] = fmaf(xv.z, wv.y, acc[2][1]);
            acc[2][2] = fmaf(xv.z, wv.z, acc[2][2]);
            acc[2][3] = fmaf(xv.z, wv.w, acc[2][3]);
            acc[3][0] = fmaf(xv.w, wv.x, acc[3][0]);
            acc[3][1] = fmaf(xv.w, wv.y, acc[3][1]);
            acc[3][2] = fmaf(xv.w, wv.z, acc[3][2]);
            acc[3][3] = fmaf(xv.w, wv.w, acc[3][3]);
        }

        float4 bv = make_float4(0.f, 0.f, 0.f, 0.f);
        if (bias) {
            bv.x = bias[4 * cg + 0]; bv.y = bias[4 * cg + 1];
            bv.z = bias[4 * cg + 2]; bv.w = bias[4 * cg + 3];
        }
#pragma unroll
        for (int i = 0; i < 4; ++i) {
            int row = n0 + 4 * m + i;
            if (row < N_) {
                float4 o;
                o.x = acc[i][0] + bv.x;
                o.y = acc[i][1] + bv.y;
                o.z = acc[i][2] + bv.z;
                o.w = acc[i][3] + bv.w;
                st4(Y + (size_t)row * ldY + 4 * cg, o);
            }
        }
    }
}

// ---------------- aggregation (fp16 H): out[d] = sum coef_e * H[src_e] + dinv[d]^2 * H[d] + bias
// one wave per node, half2 per lane; edge loop unrolled 4x for MLP
__global__ __launch_bounds__(256) void aggregate_kernel(
    const __half2* __restrict__ Hp,           // [N][64] half2
    const int* __restrict__ rowptr,
    const int2* __restrict__ edges,           // (col, coef-bits)
    const float* __restrict__ dinv, const float* __restrict__ bias,
    __half2* __restrict__ out, int N_)
{
    int wave = threadIdx.x >> 6;
    int lane = threadIdx.x & 63;
    int n = blockIdx.x * 4 + wave;
    if (n >= N_) return;

    float di = dinv[n];
    float2 self = __half22float2(Hp[(size_t)n * 64 + lane]);
    float a0 = di * di * self.x;
    float a1 = di * di * self.y;
    float b0 = 0.f, b1 = 0.f, c0 = 0.f, c1 = 0.f, d0 = 0.f, d1 = 0.f;

    int e = rowptr[n];
    const int e1 = rowptr[n + 1];
    for (; e + 3 < e1; e += 4) {
        int2 p0 = edges[e + 0];
        int2 p1 = edges[e + 1];
        int2 p2 = edges[e + 2];
        int2 p3 = edges[e + 3];
        float2 h0 = __half22float2(Hp[(size_t)p0.x * 64 + lane]);
        float2 h1 = __half22float2(Hp[(size_t)p1.x * 64 + lane]);
        float2 h2 = __half22float2(Hp[(size_t)p2.x * 64 + lane]);
        float2 h3 = __half22float2(Hp[(size_t)p3.x * 64 + lane]);
        float k0 = __int_as_float(p0.y), k1 = __int_as_float(p1.y);
        float k2 = __int_as_float(p2.y), k3 = __int_as_float(p3.y);
        a0 = fmaf(k0, h0.x, a0); a1 = fmaf(k0, h0.y, a1);
        b0 = fmaf(k1, h1.x, b0); b1 = fmaf(k1, h1.y, b1);
        c0 = fmaf(k2, h2.x, c0); c1 = fmaf(k2, h2.y, c1);
        d0 = fmaf(k3, h3.x, d0); d1 = fmaf(k3, h3.y, d1);
    }
    for (; e < e1; ++e) {
        int2 p0 = edges[e];
        float2 h0 = __half22float2(Hp[(size_t)p0.x * 64 + lane]);
        float k0 = __int_as_float(p0.y);
        a0 = fmaf(k0, h0.x, a0); a1 = fmaf(k0, h0.y, a1);
    }
    int c = lane * 2;
    float o0 = (a0 + b0) + (c0 + d0) + bias[c];
    float o1 = (a1 + b1) + (c1 + d1) + bias[c + 1];
    out[(size_t)n * 64 + lane] = __floats2half2_rn(o0, o1);
}

// ---------------- BN stats (fp16 input) ----------------
__global__ __launch_bounds__(128) void bn_stats_kernel(
    const __half* __restrict__ X, float* __restrict__ sum, float* __restrict__ sumsq, int N_)
{
    int c = threadIdx.x;  // 128
    float s = 0.f, s2 = 0.f;
    for (int n = blockIdx.x; n < N_; n += gridDim.x) {
        float v = __half2float(X[(size_t)n * H_DIM + c]);
        s += v;
        s2 = fmaf(v, v, s2);
    }
    atomicAdd(&sum[c], s);
    atomicAdd(&sumsq[c], s2);
}

__global__ __launch_bounds__(128) void bn_finalize_kernel(
    const float* __restrict__ sum, const float* __restrict__ sumsq,
    const float* __restrict__ gamma, const float* __restrict__ beta,
    float* __restrict__ A, float* __restrict__ B, int N_)
{
    int c = threadIdx.x;
    float inv_n = 1.0f / (float)N_;
    float mean = sum[c] * inv_n;
    float var = sumsq[c] * inv_n - mean * mean;
    float rstd = rsqrtf(var + 1e-5f);
    float a = rstd * gamma[c];
    A[c] = a;
    B[c] = beta[c] - mean * a;
}

// ---------------- launch ----------------
extern "C" void kernel_launch(void* const* d_in, const int* in_sizes, int n_in,
                              void* d_out, int out_size, void* d_ws, size_t ws_size,
                              hipStream_t stream) {
    const float* x   = (const float*)d_in[0];
    const int* esrc  = (const int*)d_in[1];
    const int* edst  = (const int*)d_in[2];
    const float* W1  = (const float*)d_in[3];
    const float* b1  = (const float*)d_in[4];
    const float* g1  = (const float*)d_in[5];
    const float* bt1 = (const float*)d_in[6];
    const float* W2  = (const float*)d_in[7];
    const float* b2  = (const float*)d_in[8];
    const float* g2  = (const float*)d_in[9];
    const float* bt2 = (const float*)d_in[10];
    const float* Wr  = (const float*)d_in[11];
    const float* br  = (const float*)d_in[12];

    const int N_ = in_sizes[0] / H_DIM;     // 100000
    const int E_ = in_sizes[1];             // 1600000
    const int OUTC = out_size / N_;         // 40

    // workspace carve (256B aligned)
    char* p = (char*)d_ws;
    auto alloc = [&](size_t bytes) -> void* {
        void* r = (void*)p;
        p += (bytes + 255) & ~(size_t)255;
        return r;
    };
    __half* tmpA = (__half*)alloc((size_t)N_ * H_DIM * 2);
    __half* tmpB = (__half*)alloc((size_t)N_ * H_DIM * 2);
    int2*  edges = (int2*) alloc((size_t)E_ * 8);
    int*   rowptr= (int*)  alloc((size_t)(N_ + 1) * 4);
    int*   degcur= (int*)  alloc((size_t)2 * N_ * 4);  // deg | cursor (zeroed together)
    int*   deg   = degcur;
    int*   cursor= degcur + N_;
    float* dinv  = (float*)alloc((size_t)N_ * 4);
    int*   bsum  = (int*)  alloc(4096);
    int*   boff  = (int*)  alloc(4096);
    float* bnbuf = (float*)alloc(8 * 128 * 4);
    float* sum1 = bnbuf,       *sq1 = bnbuf + 128;
    float* sum2 = bnbuf + 256, *sq2 = bnbuf + 384;
    float* A1 = bnbuf + 512, *B1 = bnbuf + 640;
    float* A2 = bnbuf + 768, *B2 = bnbuf + 896;

    hipMemsetAsync(degcur, 0, (size_t)2 * N_ * 4, stream);
    hipMemsetAsync(bnbuf, 0, 4 * 128 * 4, stream);

    const int nb = (N_ + 255) / 256;
    const int eb = (E_ + 255) / 256;
    const int ntiles = (N_ + 31) / 32;

    degree_kernel<<<eb, 256, 0, stream>>>(edst, deg, E_);
    dinv_kernel<<<nb, 256, 0, stream>>>(deg, dinv, N_);
    scan_block_kernel<<<nb, 256, 0, stream>>>(deg, rowptr, bsum, N_);
    scan_bsums_kernel<<<1, 512, 0, stream>>>(bsum, boff, nb);
    scan_add_kernel<<<nb, 256, 0, stream>>>(rowptr, boff, N_, E_);
    csr_fill_kernel<<<eb, 256, 0, stream>>>(esrc, edst, rowptr, cursor, dinv, edges, E_);

    // layer 1: h1 = x @ W1 (f32 in, fp16 out)
    gemm_kernel<128, false, float, __half><<<ntiles, 256, 0, stream>>>(
        x, W1, nullptr, nullptr, nullptr, tmpA, N_, H_DIM, H_DIM);
    aggregate_kernel<<<(N_ + 3) / 4, 256, 0, stream>>>(
        (const __half2*)tmpA, rowptr, edges, dinv, b1, (__half2*)tmpB, N_);
    bn_stats_kernel<<<512, 128, 0, stream>>>(tmpB, sum1, sq1, N_);
    bn_finalize_kernel<<<1, 128, 0, stream>>>(sum1, sq1, g1, bt1, A1, B1, N_);

    // layer 2 (BN+ReLU fused into GEMM input staging)
    gemm_kernel<128, true, __half, __half><<<ntiles, 256, 0, stream>>>(
        tmpB, W2, A1, B1, nullptr, tmpA, N_, H_DIM, H_DIM);
    aggregate_kernel<<<(N_ + 3) / 4, 256, 0, stream>>>(
        (const __half2*)tmpA, rowptr, edges, dinv, b2, (__half2*)tmpB, N_);
    bn_stats_kernel<<<512, 128, 0, stream>>>(tmpB, sum2, sq2, N_);
    bn_finalize_kernel<<<1, 128, 0, stream>>>(sum2, sq2, g2, bt2, A2, B2, N_);

    // readout (BN+ReLU fused, br fused into store, f32 out)
    gemm_kernel<64, true, __half, float><<<ntiles, 128, 0, stream>>>(
        tmpB, Wr, A2, B2, br, (float*)d_out, N_, OUTC, OUTC);
}

// Round 3
// 660.696 us; speedup vs baseline: 1.2969x; 1.0432x over previous
//
#include <hip/hip_runtime.h>
#include <hip/hip_bf16.h>
#include <hip/hip_fp16.h>

#define H_DIM 128

typedef _Float16 half8 __attribute__((ext_vector_type(8)));
typedef float floatx4 __attribute__((ext_vector_type(4)));

// ---------------- degree / dinv ----------------
__global__ void degree_kernel(const int* __restrict__ dst, int* __restrict__ deg, int E_) {
    int i = blockIdx.x * blockDim.x + threadIdx.x;
    if (i < E_) atomicAdd(&deg[dst[i]], 1);
}

__global__ void dinv_kernel(const int* __restrict__ deg, float* __restrict__ dinv, int N_) {
    int i = blockIdx.x * blockDim.x + threadIdx.x;
    if (i < N_) dinv[i] = rsqrtf((float)deg[i] + 1.0f);
}

// ---------------- exclusive scan (3-kernel) ----------------
__global__ void scan_block_kernel(const int* __restrict__ deg, int* __restrict__ rowptr,
                                  int* __restrict__ bsum, int N_) {
    __shared__ int sh[256];
    int i = blockIdx.x * 256 + threadIdx.x;
    int v = (i < N_) ? deg[i] : 0;
    sh[threadIdx.x] = v;
    __syncthreads();
    for (int off = 1; off < 256; off <<= 1) {
        int t = (threadIdx.x >= off) ? sh[threadIdx.x - off] : 0;
        __syncthreads();
        sh[threadIdx.x] += t;
        __syncthreads();
    }
    if (i < N_) rowptr[i] = sh[threadIdx.x] - v;   // exclusive
    if (threadIdx.x == 255) bsum[blockIdx.x] = sh[255];
}

__global__ void scan_bsums_kernel(const int* __restrict__ bsum, int* __restrict__ boff, int nb) {
    __shared__ int sh[512];
    int v = (threadIdx.x < nb) ? bsum[threadIdx.x] : 0;
    sh[threadIdx.x] = v;
    __syncthreads();
    for (int off = 1; off < 512; off <<= 1) {
        int t = (threadIdx.x >= off) ? sh[threadIdx.x - off] : 0;
        __syncthreads();
        sh[threadIdx.x] += t;
        __syncthreads();
    }
    if (threadIdx.x < nb) boff[threadIdx.x] = sh[threadIdx.x] - v;  // exclusive
}

__global__ void scan_add_kernel(int* __restrict__ rowptr, const int* __restrict__ boff,
                                int N_, int E_) {
    int i = blockIdx.x * 256 + threadIdx.x;
    if (i < N_) rowptr[i] += boff[blockIdx.x];
    if (i == 0) rowptr[N_] = E_;
}

// ---------------- CSR fill (col only; coef factored out via dinv row-scaling) ----------------
__global__ void csr_fill_kernel(const int* __restrict__ src, const int* __restrict__ dst,
                                const int* __restrict__ rowptr, int* __restrict__ cursor,
                                int* __restrict__ cols, int E_) {
    int i = blockIdx.x * blockDim.x + threadIdx.x;
    if (i < E_) {
        int d = dst[i];
        int p = rowptr[d] + atomicAdd(&cursor[d], 1);
        cols[p] = src[i];
    }
}

// ---------------- MFMA GEMM: Y[N,128] = dinv .* (bnrelu(X)[N,128] @ W[128,128]) ----------------
// 256 thr = 4 waves; 64 rows/block; mfma_f32_16x16x32_f16.
// A-frag: lane holds row m=lane&15, k = kb*32 + (lane>>4)*8 + j  (8 contiguous halfs -> 16B global load)
// B-frag: lane holds col n=lane&15 of tile, same k pattern; W pre-packed in LDS in frag order.
// C/D: row = (lane>>4)*4 + reg, col = lane&15.
__device__ inline half8 a_frag_f32(const float* Xr, int k0) {
    float4 v0 = *(const float4*)(Xr + k0);
    float4 v1 = *(const float4*)(Xr + k0 + 4);
    half8 a;
    a[0] = (_Float16)v0.x; a[1] = (_Float16)v0.y; a[2] = (_Float16)v0.z; a[3] = (_Float16)v0.w;
    a[4] = (_Float16)v1.x; a[5] = (_Float16)v1.y; a[6] = (_Float16)v1.z; a[7] = (_Float16)v1.w;
    return a;
}
__device__ inline half8 a_frag_f16_bn(const _Float16* Xr, int k0,
                                      const float* __restrict__ A, const float* __restrict__ B) {
    half8 r = *(const half8*)(Xr + k0);
    float4 a0 = *(const float4*)(A + k0);
    float4 a1 = *(const float4*)(A + k0 + 4);
    float4 b0 = *(const float4*)(B + k0);
    float4 b1 = *(const float4*)(B + k0 + 4);
    half8 o;
    o[0] = (_Float16)fmaxf(fmaf((float)r[0], a0.x, b0.x), 0.f);
    o[1] = (_Float16)fmaxf(fmaf((float)r[1], a0.y, b0.y), 0.f);
    o[2] = (_Float16)fmaxf(fmaf((float)r[2], a0.z, b0.z), 0.f);
    o[3] = (_Float16)fmaxf(fmaf((float)r[3], a0.w, b0.w), 0.f);
    o[4] = (_Float16)fmaxf(fmaf((float)r[4], a1.x, b1.x), 0.f);
    o[5] = (_Float16)fmaxf(fmaf((float)r[5], a1.y, b1.y), 0.f);
    o[6] = (_Float16)fmaxf(fmaf((float)r[6], a1.z, b1.z), 0.f);
    o[7] = (_Float16)fmaxf(fmaf((float)r[7], a1.w, b1.w), 0.f);
    return o;
}

template<bool BN, typename InT>
__global__ __launch_bounds__(256) void gemm_mfma_kernel(
    const InT* __restrict__ X, const float* __restrict__ W,
    const float* __restrict__ Abn, const float* __restrict__ Bbn,
    const float* __restrict__ dinv,
    _Float16* __restrict__ Y, int N_)
{
    __shared__ _Float16 Wf[32 * 64 * 8];   // 32 KB: [nt*4+kb][lane][j]

    const int tid = threadIdx.x;
    // ---- stage W[128][128] f32 -> LDS fragment order (once per block) ----
    for (int idx = tid; idx < 128 * 32; idx += 256) {
        int k = idx >> 5;                   // 0..127
        int n0 = (idx & 31) * 4;
        float4 w = *(const float4*)(W + k * 128 + n0);
        int kb = k >> 5, q = (k >> 3) & 3, j = k & 7;
#pragma unroll
        for (int u = 0; u < 4; ++u) {
            int n = n0 + u;
            int lane = (n & 15) | (q << 4);
            Wf[((((n >> 4) * 4 + kb) * 64 + lane) << 3) + j] = (_Float16)((&w.x)[u]);
        }
    }
    __syncthreads();

    const int wv = tid >> 6, lane = tid & 63;
    const int m = lane & 15, q = lane >> 4;
    const int row0 = blockIdx.x * 64 + wv * 16;

    int arow = row0 + m;
    if (arow >= N_) arow = N_ - 1;          // clamp: loads safe, stores guarded
    const InT* Xr = X + (size_t)arow * H_DIM;

    half8 a[4];
#pragma unroll
    for (int kb = 0; kb < 4; ++kb) {
        int k0 = kb * 32 + q * 8;
        if constexpr (BN) a[kb] = a_frag_f16_bn((const _Float16*)Xr, k0, Abn, Bbn);
        else              a[kb] = a_frag_f32((const float*)Xr, k0);
    }

    floatx4 acc[8];
#pragma unroll
    for (int nt = 0; nt < 8; ++nt) acc[nt] = (floatx4){0.f, 0.f, 0.f, 0.f};

#pragma unroll
    for (int nt = 0; nt < 8; ++nt) {
#pragma unroll
        for (int kb = 0; kb < 4; ++kb) {
            half8 b = *(const half8*)&Wf[(((nt * 4 + kb) * 64 + lane) << 3)];
            acc[nt] = __builtin_amdgcn_mfma_f32_16x16x32_f16(a[kb], b, acc[nt], 0, 0, 0);
        }
    }

    // ---- epilogue: scale row by dinv, store fp16 ----
#pragma unroll
    for (int r = 0; r < 4; ++r) {
        int row = row0 + q * 4 + r;
        if (row < N_) {
            float ds = dinv[row];
            _Float16* Yr = Y + (size_t)row * H_DIM + m;
#pragma unroll
            for (int nt = 0; nt < 8; ++nt)
                Yr[nt * 16] = (_Float16)(ds * acc[nt][r]);
        }
    }
}

// ---------------- vec helpers (readout VALU gemm) ----------------
__device__ inline float4 ld4(const float* p) { return *(const float4*)p; }
__device__ inline float4 ld4(const __half* p) {
    const __half2* q = (const __half2*)p;
    float2 a = __half22float2(q[0]);
    float2 b = __half22float2(q[1]);
    return make_float4(a.x, a.y, b.x, b.y);
}
__device__ inline void st4(float* p, float4 v) { *(float4*)p = v; }

// ---------------- readout GEMM (VALU): Y[N,40] = bnrelu(X)[N,128] @ Wr[128,40] + br ----------------
template<int NC, bool BN, typename InT, typename OutT>
__global__ __launch_bounds__(2 * NC) void gemm_kernel(
    const InT* __restrict__ X, const float* __restrict__ W,
    const float* __restrict__ Abn, const float* __restrict__ Bbn,
    const float* __restrict__ bias,
    OutT* __restrict__ Y, int N_, int WCOLS, int ldY)
{
    constexpr int MT = 32;
    constexpr int BLOCK = 2 * NC;
    constexpr int CHUNK = 4096 / BLOCK;
    __shared__ __align__(16) float XT[H_DIM][MT + 4];

    const int t = threadIdx.x;
    const int n0 = blockIdx.x * MT;

    {
        const int n = t & 31;
        const int kbase = (t >> 5) * CHUNK;
        int row = n0 + n;
        if (row >= N_) row = N_ - 1;
        const InT* xr = X + (size_t)row * H_DIM;
#pragma unroll
        for (int jj = 0; jj < CHUNK / 4; ++jj) {
            int k = kbase + jj * 4;
            float4 v = ld4(xr + k);
            if constexpr (BN) {
                float4 a = *(const float4*)(Abn + k);
                float4 b = *(const float4*)(Bbn + k);
                v.x = fmaxf(fmaf(v.x, a.x, b.x), 0.f);
                v.y = fmaxf(fmaf(v.y, a.y, b.y), 0.f);
                v.z = fmaxf(fmaf(v.z, a.z, b.z), 0.f);
                v.w = fmaxf(fmaf(v.w, a.w, b.w), 0.f);
            }
            XT[k + 0][n] = v.x;
            XT[k + 1][n] = v.y;
            XT[k + 2][n] = v.z;
            XT[k + 3][n] = v.w;
        }
    }
    __syncthreads();

    const int cg = t >> 3;
    const int m  = t & 7;
    if ((4 * cg) < WCOLS) {
        float acc[4][4];
#pragma unroll
        for (int i = 0; i < 4; ++i)
#pragma unroll
            for (int j = 0; j < 4; ++j) acc[i][j] = 0.f;

        const float* Wp = W + 4 * cg;
#pragma unroll 4
        for (int k = 0; k < H_DIM; ++k) {
            float4 xv = *(const float4*)&XT[k][4 * m];
            float4 wv = *(const float4*)(Wp + (size_t)k * WCOLS);
            acc[0][0] = fmaf(xv.x, wv.x, acc[0][0]);
            acc[0][1] = fmaf(xv.x, wv.y, acc[0][1]);
            acc[0][2] = fmaf(xv.x, wv.z, acc[0][2]);
            acc[0][3] = fmaf(xv.x, wv.w, acc[0][3]);
            acc[1][0] = fmaf(xv.y, wv.x, acc[1][0]);
            acc[1][1] = fmaf(xv.y, wv.y, acc[1][1]);
            acc[1][2] = fmaf(xv.y, wv.z, acc[1][2]);
            acc[1][3] = fmaf(xv.y, wv.w, acc[1][3]);
            acc[2][0] = fmaf(xv.z, wv.x, acc[2][0]);
            acc[2][1] = fmaf(xv.z, wv.y, acc[2][1]);
            acc[2][2] = fmaf(xv.z, wv.z, acc[2][2]);
            acc[2][3] = fmaf(xv.z, wv.w, acc[2][3]);
            acc[3][0] = fmaf(xv.w, wv.x, acc[3][0]);
            acc[3][1] = fmaf(xv.w, wv.y, acc[3][1]);
            acc[3][2] = fmaf(xv.w, wv.z, acc[3][2]);
            acc[3][3] = fmaf(xv.w, wv.w, acc[3][3]);
        }

        float4 bv = make_float4(0.f, 0.f, 0.f, 0.f);
        if (bias) {
            bv.x = bias[4 * cg + 0]; bv.y = bias[4 * cg + 1];
            bv.z = bias[4 * cg + 2]; bv.w = bias[4 * cg + 3];
        }
#pragma unroll
        for (int i = 0; i < 4; ++i) {
            int row = n0 + 4 * m + i;
            if (row < N_) {
                float4 o;
                o.x = acc[i][0] + bv.x;
                o.y = acc[i][1] + bv.y;
                o.z = acc[i][2] + bv.z;
                o.w = acc[i][3] + bv.w;
                st4(Y + (size_t)row * ldY + 4 * cg, o);
            }
        }
    }
}

// ---------------- aggregation: out[d] = dinv[d]*(g[d] + sum g[src_e]) + bias ----------------
__global__ __launch_bounds__(256) void aggregate_kernel(
    const __half2* __restrict__ Gp,           // [N][64] half2 (dinv-scaled h)
    const int* __restrict__ rowptr,
    const int* __restrict__ cols,
    const float* __restrict__ dinv, const float* __restrict__ bias,
    __half2* __restrict__ out, int N_)
{
    int wave = threadIdx.x >> 6;
    int lane = threadIdx.x & 63;
    int n = blockIdx.x * 4 + wave;
    if (n >= N_) return;

    float2 self = __half22float2(Gp[(size_t)n * 64 + lane]);
    float a0 = self.x, a1 = self.y;
    float b0 = 0.f, b1 = 0.f, c0 = 0.f, c1 = 0.f, d0 = 0.f, d1 = 0.f;

    int e = rowptr[n];
    const int e1 = rowptr[n + 1];
    for (; e + 3 < e1; e += 4) {
        int s0 = cols[e + 0], s1 = cols[e + 1], s2 = cols[e + 2], s3 = cols[e + 3];
        float2 h0 = __half22float2(Gp[(size_t)s0 * 64 + lane]);
        float2 h1 = __half22float2(Gp[(size_t)s1 * 64 + lane]);
        float2 h2 = __half22float2(Gp[(size_t)s2 * 64 + lane]);
        float2 h3 = __half22float2(Gp[(size_t)s3 * 64 + lane]);
        a0 += h0.x; a1 += h0.y;
        b0 += h1.x; b1 += h1.y;
        c0 += h2.x; c1 += h2.y;
        d0 += h3.x; d1 += h3.y;
    }
    for (; e < e1; ++e) {
        float2 h0 = __half22float2(Gp[(size_t)cols[e] * 64 + lane]);
        a0 += h0.x; a1 += h0.y;
    }
    float di = dinv[n];
    int c = lane * 2;
    float o0 = fmaf(di, (a0 + b0) + (c0 + d0), bias[c]);
    float o1 = fmaf(di, (a1 + b1) + (c1 + d1), bias[c + 1]);
    out[(size_t)n * 64 + lane] = __floats2half2_rn(o0, o1);
}

// ---------------- BN stats (fp16 input) ----------------
__global__ __launch_bounds__(128) void bn_stats_kernel(
    const __half* __restrict__ X, float* __restrict__ sum, float* __restrict__ sumsq, int N_)
{
    int c = threadIdx.x;  // 128
    float s = 0.f, s2 = 0.f;
    for (int n = blockIdx.x; n < N_; n += gridDim.x) {
        float v = __half2float(X[(size_t)n * H_DIM + c]);
        s += v;
        s2 = fmaf(v, v, s2);
    }
    atomicAdd(&sum[c], s);
    atomicAdd(&sumsq[c], s2);
}

__global__ __launch_bounds__(128) void bn_finalize_kernel(
    const float* __restrict__ sum, const float* __restrict__ sumsq,
    const float* __restrict__ gamma, const float* __restrict__ beta,
    float* __restrict__ A, float* __restrict__ B, int N_)
{
    int c = threadIdx.x;
    float inv_n = 1.0f / (float)N_;
    float mean = sum[c] * inv_n;
    float var = sumsq[c] * inv_n - mean * mean;
    float rstd = rsqrtf(var + 1e-5f);
    float a = rstd * gamma[c];
    A[c] = a;
    B[c] = beta[c] - mean * a;
}

// ---------------- launch ----------------
extern "C" void kernel_launch(void* const* d_in, const int* in_sizes, int n_in,
                              void* d_out, int out_size, void* d_ws, size_t ws_size,
                              hipStream_t stream) {
    const float* x   = (const float*)d_in[0];
    const int* esrc  = (const int*)d_in[1];
    const int* edst  = (const int*)d_in[2];
    const float* W1  = (const float*)d_in[3];
    const float* b1  = (const float*)d_in[4];
    const float* g1  = (const float*)d_in[5];
    const float* bt1 = (const float*)d_in[6];
    const float* W2  = (const float*)d_in[7];
    const float* b2  = (const float*)d_in[8];
    const float* g2  = (const float*)d_in[9];
    const float* bt2 = (const float*)d_in[10];
    const float* Wr  = (const float*)d_in[11];
    const float* br  = (const float*)d_in[12];

    const int N_ = in_sizes[0] / H_DIM;     // 100000
    const int E_ = in_sizes[1];             // 1600000
    const int OUTC = out_size / N_;         // 40

    char* p = (char*)d_ws;
    auto alloc = [&](size_t bytes) -> void* {
        void* r = (void*)p;
        p += (bytes + 255) & ~(size_t)255;
        return r;
    };
    __half* tmpA = (__half*)alloc((size_t)N_ * H_DIM * 2);
    __half* tmpB = (__half*)alloc((size_t)N_ * H_DIM * 2);
    int*   cols  = (int*)  alloc((size_t)E_ * 4);
    int*   rowptr= (int*)  alloc((size_t)(N_ + 1) * 4);
    int*   degcur= (int*)  alloc((size_t)2 * N_ * 4);
    int*   deg   = degcur;
    int*   cursor= degcur + N_;
    float* dinv  = (float*)alloc((size_t)N_ * 4);
    int*   bsum  = (int*)  alloc(4096);
    int*   boff  = (int*)  alloc(4096);
    float* bnbuf = (float*)alloc(8 * 128 * 4);
    float* sum1 = bnbuf,       *sq1 = bnbuf + 128;
    float* sum2 = bnbuf + 256, *sq2 = bnbuf + 384;
    float* A1 = bnbuf + 512, *B1 = bnbuf + 640;
    float* A2 = bnbuf + 768, *B2 = bnbuf + 896;

    hipMemsetAsync(degcur, 0, (size_t)2 * N_ * 4, stream);
    hipMemsetAsync(bnbuf, 0, 4 * 128 * 4, stream);

    const int nb = (N_ + 255) / 256;
    const int eb = (E_ + 255) / 256;
    const int ntiles32 = (N_ + 31) / 32;
    const int ntiles64 = (N_ + 63) / 64;

    degree_kernel<<<eb, 256, 0, stream>>>(edst, deg, E_);
    dinv_kernel<<<nb, 256, 0, stream>>>(deg, dinv, N_);
    scan_block_kernel<<<nb, 256, 0, stream>>>(deg, rowptr, bsum, N_);
    scan_bsums_kernel<<<1, 512, 0, stream>>>(bsum, boff, nb);
    scan_add_kernel<<<nb, 256, 0, stream>>>(rowptr, boff, N_, E_);
    csr_fill_kernel<<<eb, 256, 0, stream>>>(esrc, edst, rowptr, cursor, cols, E_);

    // layer 1: g1 = dinv .* (x @ W1)   (f32 in, fp16 out, MFMA)
    gemm_mfma_kernel<false, float><<<ntiles64, 256, 0, stream>>>(
        x, W1, nullptr, nullptr, dinv, (_Float16*)tmpA, N_);
    aggregate_kernel<<<(N_ + 3) / 4, 256, 0, stream>>>(
        (const __half2*)tmpA, rowptr, cols, dinv, b1, (__half2*)tmpB, N_);
    bn_stats_kernel<<<512, 128, 0, stream>>>(tmpB, sum1, sq1, N_);
    bn_finalize_kernel<<<1, 128, 0, stream>>>(sum1, sq1, g1, bt1, A1, B1, N_);

    // layer 2: g2 = dinv .* (bnrelu(h1) @ W2)   (fp16 in/out, MFMA, BN fused)
    gemm_mfma_kernel<true, _Float16><<<ntiles64, 256, 0, stream>>>(
        (const _Float16*)tmpB, W2, A1, B1, dinv, (_Float16*)tmpA, N_);
    aggregate_kernel<<<(N_ + 3) / 4, 256, 0, stream>>>(
        (const __half2*)tmpA, rowptr, cols, dinv, b2, (__half2*)tmpB, N_);
    bn_stats_kernel<<<512, 128, 0, stream>>>(tmpB, sum2, sq2, N_);
    bn_finalize_kernel<<<1, 128, 0, stream>>>(sum2, sq2, g2, bt2, A2, B2, N_);

    // readout (VALU, BN+bias fused, f32 out)
    gemm_kernel<64, true, __half, float><<<ntiles32, 128, 0, stream>>>(
        tmpB, Wr, A2, B2, br, (float*)d_out, N_, OUTC, OUTC);
}

// Round 4
// 575.646 us; speedup vs baseline: 1.4885x; 1.1477x over previous
//
#include <hip/hip_runtime.h>
#include <hip/hip_bf16.h>
#include <hip/hip_fp16.h>

#define H_DIM 128

typedef _Float16 half8 __attribute__((ext_vector_type(8)));
typedef float floatx4 __attribute__((ext_vector_type(4)));

// ---------------- degree / dinv ----------------
__global__ void degree_kernel(const int* __restrict__ dst, int* __restrict__ deg, int E_) {
    int i = blockIdx.x * blockDim.x + threadIdx.x;
    if (i < E_) atomicAdd(&deg[dst[i]], 1);
}

__global__ void dinv_kernel(const int* __restrict__ deg, float* __restrict__ dinv, int N_) {
    int i = blockIdx.x * blockDim.x + threadIdx.x;
    if (i < N_) dinv[i] = rsqrtf((float)deg[i] + 1.0f);
}

// ---------------- exclusive scan (3-kernel) ----------------
__global__ void scan_block_kernel(const int* __restrict__ deg, int* __restrict__ rowptr,
                                  int* __restrict__ bsum, int N_) {
    __shared__ int sh[256];
    int i = blockIdx.x * 256 + threadIdx.x;
    int v = (i < N_) ? deg[i] : 0;
    sh[threadIdx.x] = v;
    __syncthreads();
    for (int off = 1; off < 256; off <<= 1) {
        int t = (threadIdx.x >= off) ? sh[threadIdx.x - off] : 0;
        __syncthreads();
        sh[threadIdx.x] += t;
        __syncthreads();
    }
    if (i < N_) rowptr[i] = sh[threadIdx.x] - v;   // exclusive
    if (threadIdx.x == 255) bsum[blockIdx.x] = sh[255];
}

__global__ void scan_bsums_kernel(const int* __restrict__ bsum, int* __restrict__ boff, int nb) {
    __shared__ int sh[512];
    int v = (threadIdx.x < nb) ? bsum[threadIdx.x] : 0;
    sh[threadIdx.x] = v;
    __syncthreads();
    for (int off = 1; off < 512; off <<= 1) {
        int t = (threadIdx.x >= off) ? sh[threadIdx.x - off] : 0;
        __syncthreads();
        sh[threadIdx.x] += t;
        __syncthreads();
    }
    if (threadIdx.x < nb) boff[threadIdx.x] = sh[threadIdx.x] - v;  // exclusive
}

__global__ void scan_add_kernel(int* __restrict__ rowptr, const int* __restrict__ boff,
                                int N_, int E_) {
    int i = blockIdx.x * 256 + threadIdx.x;
    if (i < N_) rowptr[i] += boff[blockIdx.x];
    if (i == 0) rowptr[N_] = E_;
}

// ---------------- CSR fill, XCD-binned by dst bucket ----------------
// bucket(d) = d >> shift (0..6 for N=100K). blockIdx%8 == bucket; every
// (chunk,bucket) pair covered exactly once => correctness independent of
// block->XCD mapping; locality benefits if mapping is round-robin %8.
__global__ void csr_fill_kernel(const int* __restrict__ src, const int* __restrict__ dst,
                                const int* __restrict__ rowptr, int* __restrict__ cursor,
                                int* __restrict__ cols, int E_, int N_, int shift) {
    int b = blockIdx.x & 7;
    if (((N_ - 1) >> shift) < b) return;          // bucket never occurs
    int i = (blockIdx.x >> 3) * blockDim.x + threadIdx.x;
    if (i < E_) {
        int d = dst[i];
        if ((d >> shift) == b) {
            int p = rowptr[d] + atomicAdd(&cursor[d], 1);
            cols[p] = src[i];
        }
    }
}

// ---------------- MFMA GEMM: Y[N,128] = dinv .* (bnrelu(X)[N,128] @ W[128,128]) ----------------
__device__ inline half8 a_frag_f32(const float* Xr, int k0) {
    float4 v0 = *(const float4*)(Xr + k0);
    float4 v1 = *(const float4*)(Xr + k0 + 4);
    half8 a;
    a[0] = (_Float16)v0.x; a[1] = (_Float16)v0.y; a[2] = (_Float16)v0.z; a[3] = (_Float16)v0.w;
    a[4] = (_Float16)v1.x; a[5] = (_Float16)v1.y; a[6] = (_Float16)v1.z; a[7] = (_Float16)v1.w;
    return a;
}
__device__ inline half8 a_frag_f16_bn(const _Float16* Xr, int k0,
                                      const float* __restrict__ A, const float* __restrict__ B) {
    half8 r = *(const half8*)(Xr + k0);
    float4 a0 = *(const float4*)(A + k0);
    float4 a1 = *(const float4*)(A + k0 + 4);
    float4 b0 = *(const float4*)(B + k0);
    float4 b1 = *(const float4*)(B + k0 + 4);
    half8 o;
    o[0] = (_Float16)fmaxf(fmaf((float)r[0], a0.x, b0.x), 0.f);
    o[1] = (_Float16)fmaxf(fmaf((float)r[1], a0.y, b0.y), 0.f);
    o[2] = (_Float16)fmaxf(fmaf((float)r[2], a0.z, b0.z), 0.f);
    o[3] = (_Float16)fmaxf(fmaf((float)r[3], a0.w, b0.w), 0.f);
    o[4] = (_Float16)fmaxf(fmaf((float)r[4], a1.x, b1.x), 0.f);
    o[5] = (_Float16)fmaxf(fmaf((float)r[5], a1.y, b1.y), 0.f);
    o[6] = (_Float16)fmaxf(fmaf((float)r[6], a1.z, b1.z), 0.f);
    o[7] = (_Float16)fmaxf(fmaf((float)r[7], a1.w, b1.w), 0.f);
    return o;
}

template<bool BN, typename InT>
__global__ __launch_bounds__(256) void gemm_mfma_kernel(
    const InT* __restrict__ X, const float* __restrict__ W,
    const float* __restrict__ Abn, const float* __restrict__ Bbn,
    const float* __restrict__ dinv,
    _Float16* __restrict__ Y, int N_)
{
    __shared__ _Float16 Wf[32 * 64 * 8];   // 32 KB: [nt*4+kb][lane][j]

    const int tid = threadIdx.x;
    for (int idx = tid; idx < 128 * 32; idx += 256) {
        int k = idx >> 5;                   // 0..127
        int n0 = (idx & 31) * 4;
        float4 w = *(const float4*)(W + k * 128 + n0);
        int kb = k >> 5, q = (k >> 3) & 3, j = k & 7;
#pragma unroll
        for (int u = 0; u < 4; ++u) {
            int n = n0 + u;
            int lane = (n & 15) | (q << 4);
            Wf[((((n >> 4) * 4 + kb) * 64 + lane) << 3) + j] = (_Float16)((&w.x)[u]);
        }
    }
    __syncthreads();

    const int wv = tid >> 6, lane = tid & 63;
    const int m = lane & 15, q = lane >> 4;
    const int row0 = blockIdx.x * 64 + wv * 16;

    int arow = row0 + m;
    if (arow >= N_) arow = N_ - 1;
    const InT* Xr = X + (size_t)arow * H_DIM;

    half8 a[4];
#pragma unroll
    for (int kb = 0; kb < 4; ++kb) {
        int k0 = kb * 32 + q * 8;
        if constexpr (BN) a[kb] = a_frag_f16_bn((const _Float16*)Xr, k0, Abn, Bbn);
        else              a[kb] = a_frag_f32((const float*)Xr, k0);
    }

    floatx4 acc[8];
#pragma unroll
    for (int nt = 0; nt < 8; ++nt) acc[nt] = (floatx4){0.f, 0.f, 0.f, 0.f};

#pragma unroll
    for (int nt = 0; nt < 8; ++nt) {
#pragma unroll
        for (int kb = 0; kb < 4; ++kb) {
            half8 b = *(const half8*)&Wf[(((nt * 4 + kb) * 64 + lane) << 3)];
            acc[nt] = __builtin_amdgcn_mfma_f32_16x16x32_f16(a[kb], b, acc[nt], 0, 0, 0);
        }
    }

#pragma unroll
    for (int r = 0; r < 4; ++r) {
        int row = row0 + q * 4 + r;
        if (row < N_) {
            float ds = dinv[row];
            _Float16* Yr = Y + (size_t)row * H_DIM + m;
#pragma unroll
            for (int nt = 0; nt < 8; ++nt)
                Yr[nt * 16] = (_Float16)(ds * acc[nt][r]);
        }
    }
}

// ---------------- vec helpers (readout VALU gemm) ----------------
__device__ inline float4 ld4(const float* p) { return *(const float4*)p; }
__device__ inline float4 ld4(const __half* p) {
    const __half2* q = (const __half2*)p;
    float2 a = __half22float2(q[0]);
    float2 b = __half22float2(q[1]);
    return make_float4(a.x, a.y, b.x, b.y);
}
__device__ inline void st4(float* p, float4 v) { *(float4*)p = v; }

// ---------------- readout GEMM (VALU): Y[N,40] = bnrelu(X)[N,128] @ Wr[128,40] + br ----------------
template<int NC, bool BN, typename InT, typename OutT>
__global__ __launch_bounds__(2 * NC) void gemm_kernel(
    const InT* __restrict__ X, const float* __restrict__ W,
    const float* __restrict__ Abn, const float* __restrict__ Bbn,
    const float* __restrict__ bias,
    OutT* __restrict__ Y, int N_, int WCOLS, int ldY)
{
    constexpr int MT = 32;
    constexpr int BLOCK = 2 * NC;
    constexpr int CHUNK = 4096 / BLOCK;
    __shared__ __align__(16) float XT[H_DIM][MT + 4];

    const int t = threadIdx.x;
    const int n0 = blockIdx.x * MT;

    {
        const int n = t & 31;
        const int kbase = (t >> 5) * CHUNK;
        int row = n0 + n;
        if (row >= N_) row = N_ - 1;
        const InT* xr = X + (size_t)row * H_DIM;
#pragma unroll
        for (int jj = 0; jj < CHUNK / 4; ++jj) {
            int k = kbase + jj * 4;
            float4 v = ld4(xr + k);
            if constexpr (BN) {
                float4 a = *(const float4*)(Abn + k);
                float4 b = *(const float4*)(Bbn + k);
                v.x = fmaxf(fmaf(v.x, a.x, b.x), 0.f);
                v.y = fmaxf(fmaf(v.y, a.y, b.y), 0.f);
                v.z = fmaxf(fmaf(v.z, a.z, b.z), 0.f);
                v.w = fmaxf(fmaf(v.w, a.w, b.w), 0.f);
            }
            XT[k + 0][n] = v.x;
            XT[k + 1][n] = v.y;
            XT[k + 2][n] = v.z;
            XT[k + 3][n] = v.w;
        }
    }
    __syncthreads();

    const int cg = t >> 3;
    const int m  = t & 7;
    if ((4 * cg) < WCOLS) {
        float acc[4][4];
#pragma unroll
        for (int i = 0; i < 4; ++i)
#pragma unroll
            for (int j = 0; j < 4; ++j) acc[i][j] = 0.f;

        const float* Wp = W + 4 * cg;
#pragma unroll 4
        for (int k = 0; k < H_DIM; ++k) {
            float4 xv = *(const float4*)&XT[k][4 * m];
            float4 wv = *(const float4*)(Wp + (size_t)k * WCOLS);
            acc[0][0] = fmaf(xv.x, wv.x, acc[0][0]);
            acc[0][1] = fmaf(xv.x, wv.y, acc[0][1]);
            acc[0][2] = fmaf(xv.x, wv.z, acc[0][2]);
            acc[0][3] = fmaf(xv.x, wv.w, acc[0][3]);
            acc[1][0] = fmaf(xv.y, wv.x, acc[1][0]);
            acc[1][1] = fmaf(xv.y, wv.y, acc[1][1]);
            acc[1][2] = fmaf(xv.y, wv.z, acc[1][2]);
            acc[1][3] = fmaf(xv.y, wv.w, acc[1][3]);
            acc[2][0] = fmaf(xv.z, wv.x, acc[2][0]);
            acc[2][1] = fmaf(xv.z, wv.y, acc[2][1]);
            acc[2][2] = fmaf(xv.z, wv.z, acc[2][2]);
            acc[2][3] = fmaf(xv.z, wv.w, acc[2][3]);
            acc[3][0] = fmaf(xv.w, wv.x, acc[3][0]);
            acc[3][1] = fmaf(xv.w, wv.y, acc[3][1]);
            acc[3][2] = fmaf(xv.w, wv.z, acc[3][2]);
            acc[3][3] = fmaf(xv.w, wv.w, acc[3][3]);
        }

        float4 bv = make_float4(0.f, 0.f, 0.f, 0.f);
        if (bias) {
            bv.x = bias[4 * cg + 0]; bv.y = bias[4 * cg + 1];
            bv.z = bias[4 * cg + 2]; bv.w = bias[4 * cg + 3];
        }
#pragma unroll
        for (int i = 0; i < 4; ++i) {
            int row = n0 + 4 * m + i;
            if (row < N_) {
                float4 o;
                o.x = acc[i][0] + bv.x;
                o.y = acc[i][1] + bv.y;
                o.z = acc[i][2] + bv.z;
                o.w = acc[i][3] + bv.w;
                st4(Y + (size_t)row * ldY + 4 * cg, o);
            }
        }
    }
}

// ---------------- aggregation + fused BN stats ----------------
// out[d] = dinv[d]*(g[d] + sum g[src_e]) + bias; per-lane register accum of
// sum/sumsq for its fixed channel pair, LDS-combined, 128 atomics/block.
__global__ __launch_bounds__(256) void aggregate_kernel(
    const __half2* __restrict__ Gp,           // [N][64] half2 (dinv-scaled h)
    const int* __restrict__ rowptr,
    const int* __restrict__ cols,
    const float* __restrict__ dinv, const float* __restrict__ bias,
    __half2* __restrict__ out,
    float* __restrict__ gsum, float* __restrict__ gsq,
    int N_, int stride)
{
    __shared__ float ssum[4][128], ssq[4][128];
    const int wave = threadIdx.x >> 6;
    const int lane = threadIdx.x & 63;
    const int c = lane * 2;
    const float bs0 = bias[c], bs1 = bias[c + 1];
    float rs0 = 0.f, rs1 = 0.f, rq0 = 0.f, rq1 = 0.f;

    for (int n = blockIdx.x * 4 + wave; n < N_; n += stride) {
        float2 self = __half22float2(Gp[(size_t)n * 64 + lane]);
        float a0 = self.x, a1 = self.y;
        float b0 = 0.f, b1 = 0.f, c0 = 0.f, c1 = 0.f, d0 = 0.f, d1 = 0.f;

        int e = rowptr[n];
        const int e1 = rowptr[n + 1];
        for (; e + 3 < e1; e += 4) {
            int s0 = cols[e + 0], s1 = cols[e + 1], s2 = cols[e + 2], s3 = cols[e + 3];
            float2 h0 = __half22float2(Gp[(size_t)s0 * 64 + lane]);
            float2 h1 = __half22float2(Gp[(size_t)s1 * 64 + lane]);
            float2 h2 = __half22float2(Gp[(size_t)s2 * 64 + lane]);
            float2 h3 = __half22float2(Gp[(size_t)s3 * 64 + lane]);
            a0 += h0.x; a1 += h0.y;
            b0 += h1.x; b1 += h1.y;
            c0 += h2.x; c1 += h2.y;
            d0 += h3.x; d1 += h3.y;
        }
        for (; e < e1; ++e) {
            float2 h0 = __half22float2(Gp[(size_t)cols[e] * 64 + lane]);
            a0 += h0.x; a1 += h0.y;
        }
        float di = dinv[n];
        float o0 = fmaf(di, (a0 + b0) + (c0 + d0), bs0);
        float o1 = fmaf(di, (a1 + b1) + (c1 + d1), bs1);
        out[(size_t)n * 64 + lane] = __floats2half2_rn(o0, o1);
        rs0 += o0; rs1 += o1;
        rq0 = fmaf(o0, o0, rq0); rq1 = fmaf(o1, o1, rq1);
    }

    ssum[wave][c] = rs0; ssum[wave][c + 1] = rs1;
    ssq[wave][c]  = rq0; ssq[wave][c + 1]  = rq1;
    __syncthreads();
    if (threadIdx.x < 128) {
        int k = threadIdx.x;
        float s = (ssum[0][k] + ssum[1][k]) + (ssum[2][k] + ssum[3][k]);
        float q = (ssq[0][k] + ssq[1][k]) + (ssq[2][k] + ssq[3][k]);
        atomicAdd(&gsum[k], s);
        atomicAdd(&gsq[k], q);
    }
}

__global__ __launch_bounds__(128) void bn_finalize_kernel(
    const float* __restrict__ sum, const float* __restrict__ sumsq,
    const float* __restrict__ gamma, const float* __restrict__ beta,
    float* __restrict__ A, float* __restrict__ B, int N_)
{
    int c = threadIdx.x;
    float inv_n = 1.0f / (float)N_;
    float mean = sum[c] * inv_n;
    float var = sumsq[c] * inv_n - mean * mean;
    float rstd = rsqrtf(var + 1e-5f);
    float a = rstd * gamma[c];
    A[c] = a;
    B[c] = beta[c] - mean * a;
}

// ---------------- launch ----------------
extern "C" void kernel_launch(void* const* d_in, const int* in_sizes, int n_in,
                              void* d_out, int out_size, void* d_ws, size_t ws_size,
                              hipStream_t stream) {
    const float* x   = (const float*)d_in[0];
    const int* esrc  = (const int*)d_in[1];
    const int* edst  = (const int*)d_in[2];
    const float* W1  = (const float*)d_in[3];
    const float* b1  = (const float*)d_in[4];
    const float* g1  = (const float*)d_in[5];
    const float* bt1 = (const float*)d_in[6];
    const float* W2  = (const float*)d_in[7];
    const float* b2  = (const float*)d_in[8];
    const float* g2  = (const float*)d_in[9];
    const float* bt2 = (const float*)d_in[10];
    const float* Wr  = (const float*)d_in[11];
    const float* br  = (const float*)d_in[12];

    const int N_ = in_sizes[0] / H_DIM;     // 100000
    const int E_ = in_sizes[1];             // 1600000
    const int OUTC = out_size / N_;         // 40

    char* p = (char*)d_ws;
    auto alloc = [&](size_t bytes) -> void* {
        void* r = (void*)p;
        p += (bytes + 255) & ~(size_t)255;
        return r;
    };
    __half* tmpA = (__half*)alloc((size_t)N_ * H_DIM * 2);
    __half* tmpB = (__half*)alloc((size_t)N_ * H_DIM * 2);
    int*   cols  = (int*)  alloc((size_t)E_ * 4);
    int*   rowptr= (int*)  alloc((size_t)(N_ + 1) * 4);
    int*   degcur= (int*)  alloc((size_t)2 * N_ * 4);
    int*   deg   = degcur;
    int*   cursor= degcur + N_;
    float* dinv  = (float*)alloc((size_t)N_ * 4);
    int*   bsum  = (int*)  alloc(4096);
    int*   boff  = (int*)  alloc(4096);
    float* bnbuf = (float*)alloc(8 * 128 * 4);
    float* sum1 = bnbuf,       *sq1 = bnbuf + 128;
    float* sum2 = bnbuf + 256, *sq2 = bnbuf + 384;
    float* A1 = bnbuf + 512, *B1 = bnbuf + 640;
    float* A2 = bnbuf + 768, *B2 = bnbuf + 896;

    hipMemsetAsync(degcur, 0, (size_t)2 * N_ * 4, stream);
    hipMemsetAsync(bnbuf, 0, 4 * 128 * 4, stream);

    const int nb = (N_ + 255) / 256;
    const int eb = (E_ + 255) / 256;
    const int ntiles32 = (N_ + 31) / 32;
    const int ntiles64 = (N_ + 63) / 64;

    int shift = 0;                           // buckets (d>>shift) in 0..7
    while (((N_ - 1) >> shift) > 7) ++shift; // N=100000 -> shift=14, buckets 0..6

    const int AGG_BLOCKS = 2048;
    const int AGG_STRIDE = AGG_BLOCKS * 4;

    degree_kernel<<<eb, 256, 0, stream>>>(edst, deg, E_);
    dinv_kernel<<<nb, 256, 0, stream>>>(deg, dinv, N_);
    scan_block_kernel<<<nb, 256, 0, stream>>>(deg, rowptr, bsum, N_);
    scan_bsums_kernel<<<1, 512, 0, stream>>>(bsum, boff, nb);
    scan_add_kernel<<<nb, 256, 0, stream>>>(rowptr, boff, N_, E_);
    csr_fill_kernel<<<eb * 8, 256, 0, stream>>>(esrc, edst, rowptr, cursor, cols, E_, N_, shift);

    // layer 1: g1 = dinv .* (x @ W1)   (f32 in, fp16 out, MFMA)
    gemm_mfma_kernel<false, float><<<ntiles64, 256, 0, stream>>>(
        x, W1, nullptr, nullptr, dinv, (_Float16*)tmpA, N_);
    aggregate_kernel<<<AGG_BLOCKS, 256, 0, stream>>>(
        (const __half2*)tmpA, rowptr, cols, dinv, b1, (__half2*)tmpB,
        sum1, sq1, N_, AGG_STRIDE);
    bn_finalize_kernel<<<1, 128, 0, stream>>>(sum1, sq1, g1, bt1, A1, B1, N_);

    // layer 2: g2 = dinv .* (bnrelu(h1) @ W2)   (fp16 in/out, MFMA, BN fused)
    gemm_mfma_kernel<true, _Float16><<<ntiles64, 256, 0, stream>>>(
        (const _Float16*)tmpB, W2, A1, B1, dinv, (_Float16*)tmpA, N_);
    aggregate_kernel<<<AGG_BLOCKS, 256, 0, stream>>>(
        (const __half2*)tmpA, rowptr, cols, dinv, b2, (__half2*)tmpB,
        sum2, sq2, N_, AGG_STRIDE);
    bn_finalize_kernel<<<1, 128, 0, stream>>>(sum2, sq2, g2, bt2, A2, B2, N_);

    // readout (VALU, BN+bias fused, f32 out)
    gemm_kernel<64, true, __half, float><<<ntiles32, 128, 0, stream>>>(
        tmpB, Wr, A2, B2, br, (float*)d_out, N_, OUTC, OUTC);
}

// Round 5
// 572.537 us; speedup vs baseline: 1.4966x; 1.0054x over previous
//
#include <hip/hip_runtime.h>
#include <hip/hip_bf16.h>
#include <hip/hip_fp16.h>

#define H_DIM 128

typedef _Float16 half8 __attribute__((ext_vector_type(8)));
typedef float floatx4 __attribute__((ext_vector_type(4)));

// ---------------- degree / dinv ----------------
__global__ void degree_kernel(const int* __restrict__ dst, int* __restrict__ deg, int E_) {
    int i = blockIdx.x * blockDim.x + threadIdx.x;
    if (i < E_) atomicAdd(&deg[dst[i]], 1);
}

__global__ void dinv_kernel(const int* __restrict__ deg, float* __restrict__ dinv, int N_) {
    int i = blockIdx.x * blockDim.x + threadIdx.x;
    if (i < N_) dinv[i] = rsqrtf((float)deg[i] + 1.0f);
}

// ---------------- exclusive scan (3-kernel) ----------------
__global__ void scan_block_kernel(const int* __restrict__ deg, int* __restrict__ rowptr,
                                  int* __restrict__ bsum, int N_) {
    __shared__ int sh[256];
    int i = blockIdx.x * 256 + threadIdx.x;
    int v = (i < N_) ? deg[i] : 0;
    sh[threadIdx.x] = v;
    __syncthreads();
    for (int off = 1; off < 256; off <<= 1) {
        int t = (threadIdx.x >= off) ? sh[threadIdx.x - off] : 0;
        __syncthreads();
        sh[threadIdx.x] += t;
        __syncthreads();
    }
    if (i < N_) rowptr[i] = sh[threadIdx.x] - v;   // exclusive
    if (threadIdx.x == 255) bsum[blockIdx.x] = sh[255];
}

__global__ void scan_bsums_kernel(const int* __restrict__ bsum, int* __restrict__ boff, int nb) {
    __shared__ int sh[512];
    int v = (threadIdx.x < nb) ? bsum[threadIdx.x] : 0;
    sh[threadIdx.x] = v;
    __syncthreads();
    for (int off = 1; off < 512; off <<= 1) {
        int t = (threadIdx.x >= off) ? sh[threadIdx.x - off] : 0;
        __syncthreads();
        sh[threadIdx.x] += t;
        __syncthreads();
    }
    if (threadIdx.x < nb) boff[threadIdx.x] = sh[threadIdx.x] - v;  // exclusive
}

__global__ void scan_add_kernel(int* __restrict__ rowptr, const int* __restrict__ boff,
                                int N_, int E_) {
    int i = blockIdx.x * 256 + threadIdx.x;
    if (i < N_) rowptr[i] += boff[blockIdx.x];
    if (i == 0) rowptr[N_] = E_;
}

// ---------------- CSR fill, XCD-binned by dst bucket ----------------
__global__ void csr_fill_kernel(const int* __restrict__ src, const int* __restrict__ dst,
                                const int* __restrict__ rowptr, int* __restrict__ cursor,
                                int* __restrict__ cols, int E_, int N_, int shift) {
    int b = blockIdx.x & 7;
    if (((N_ - 1) >> shift) < b) return;          // bucket never occurs
    int i = (blockIdx.x >> 3) * blockDim.x + threadIdx.x;
    if (i < E_) {
        int d = dst[i];
        if ((d >> shift) == b) {
            int p = rowptr[d] + atomicAdd(&cursor[d], 1);
            cols[p] = src[i];
        }
    }
}

// ---------------- MFMA GEMM: Y[N,128] = dinv .* (bnrelu(X)[N,128] @ W[128,128]) ----------------
__device__ inline half8 a_frag_f32(const float* Xr, int k0) {
    float4 v0 = *(const float4*)(Xr + k0);
    float4 v1 = *(const float4*)(Xr + k0 + 4);
    half8 a;
    a[0] = (_Float16)v0.x; a[1] = (_Float16)v0.y; a[2] = (_Float16)v0.z; a[3] = (_Float16)v0.w;
    a[4] = (_Float16)v1.x; a[5] = (_Float16)v1.y; a[6] = (_Float16)v1.z; a[7] = (_Float16)v1.w;
    return a;
}
__device__ inline half8 a_frag_f16_bn(const _Float16* Xr, int k0,
                                      const float* __restrict__ A, const float* __restrict__ B) {
    half8 r = *(const half8*)(Xr + k0);
    float4 a0 = *(const float4*)(A + k0);
    float4 a1 = *(const float4*)(A + k0 + 4);
    float4 b0 = *(const float4*)(B + k0);
    float4 b1 = *(const float4*)(B + k0 + 4);
    half8 o;
    o[0] = (_Float16)fmaxf(fmaf((float)r[0], a0.x, b0.x), 0.f);
    o[1] = (_Float16)fmaxf(fmaf((float)r[1], a0.y, b0.y), 0.f);
    o[2] = (_Float16)fmaxf(fmaf((float)r[2], a0.z, b0.z), 0.f);
    o[3] = (_Float16)fmaxf(fmaf((float)r[3], a0.w, b0.w), 0.f);
    o[4] = (_Float16)fmaxf(fmaf((float)r[4], a1.x, b1.x), 0.f);
    o[5] = (_Float16)fmaxf(fmaf((float)r[5], a1.y, b1.y), 0.f);
    o[6] = (_Float16)fmaxf(fmaf((float)r[6], a1.z, b1.z), 0.f);
    o[7] = (_Float16)fmaxf(fmaf((float)r[7], a1.w, b1.w), 0.f);
    return o;
}

template<bool BN, typename InT>
__global__ __launch_bounds__(256) void gemm_mfma_kernel(
    const InT* __restrict__ X, const float* __restrict__ W,
    const float* __restrict__ Abn, const float* __restrict__ Bbn,
    const float* __restrict__ dinv,
    _Float16* __restrict__ Y, int N_)
{
    __shared__ _Float16 Wf[32 * 64 * 8];   // 32 KB: [nt*4+kb][lane][j]

    const int tid = threadIdx.x;
    for (int idx = tid; idx < 128 * 32; idx += 256) {
        int k = idx >> 5;                   // 0..127
        int n0 = (idx & 31) * 4;
        float4 w = *(const float4*)(W + k * 128 + n0);
        int kb = k >> 5, q = (k >> 3) & 3, j = k & 7;
#pragma unroll
        for (int u = 0; u < 4; ++u) {
            int n = n0 + u;
            int lane = (n & 15) | (q << 4);
            Wf[((((n >> 4) * 4 + kb) * 64 + lane) << 3) + j] = (_Float16)((&w.x)[u]);
        }
    }
    __syncthreads();

    const int wv = tid >> 6, lane = tid & 63;
    const int m = lane & 15, q = lane >> 4;
    const int row0 = blockIdx.x * 64 + wv * 16;

    int arow = row0 + m;
    if (arow >= N_) arow = N_ - 1;
    const InT* Xr = X + (size_t)arow * H_DIM;

    half8 a[4];
#pragma unroll
    for (int kb = 0; kb < 4; ++kb) {
        int k0 = kb * 32 + q * 8;
        if constexpr (BN) a[kb] = a_frag_f16_bn((const _Float16*)Xr, k0, Abn, Bbn);
        else              a[kb] = a_frag_f32((const float*)Xr, k0);
    }

    floatx4 acc[8];
#pragma unroll
    for (int nt = 0; nt < 8; ++nt) acc[nt] = (floatx4){0.f, 0.f, 0.f, 0.f};

#pragma unroll
    for (int nt = 0; nt < 8; ++nt) {
#pragma unroll
        for (int kb = 0; kb < 4; ++kb) {
            half8 b = *(const half8*)&Wf[(((nt * 4 + kb) * 64 + lane) << 3)];
            acc[nt] = __builtin_amdgcn_mfma_f32_16x16x32_f16(a[kb], b, acc[nt], 0, 0, 0);
        }
    }

#pragma unroll
    for (int r = 0; r < 4; ++r) {
        int row = row0 + q * 4 + r;
        if (row < N_) {
            float ds = dinv[row];
            _Float16* Yr = Y + (size_t)row * H_DIM + m;
#pragma unroll
            for (int nt = 0; nt < 8; ++nt)
                Yr[nt * 16] = (_Float16)(ds * acc[nt][r]);
        }
    }
}

// ---------------- vec helpers (readout VALU gemm) ----------------
__device__ inline float4 ld4(const float* p) { return *(const float4*)p; }
__device__ inline float4 ld4(const __half* p) {
    const __half2* q = (const __half2*)p;
    float2 a = __half22float2(q[0]);
    float2 b = __half22float2(q[1]);
    return make_float4(a.x, a.y, b.x, b.y);
}
__device__ inline void st4(float* p, float4 v) { *(float4*)p = v; }

// ---------------- readout GEMM (VALU): Y[N,40] = bnrelu(X)[N,128] @ Wr[128,40] + br ----------------
template<int NC, bool BN, typename InT, typename OutT>
__global__ __launch_bounds__(2 * NC) void gemm_kernel(
    const InT* __restrict__ X, const float* __restrict__ W,
    const float* __restrict__ Abn, const float* __restrict__ Bbn,
    const float* __restrict__ bias,
    OutT* __restrict__ Y, int N_, int WCOLS, int ldY)
{
    constexpr int MT = 32;
    constexpr int BLOCK = 2 * NC;
    constexpr int CHUNK = 4096 / BLOCK;
    __shared__ __align__(16) float XT[H_DIM][MT + 4];

    const int t = threadIdx.x;
    const int n0 = blockIdx.x * MT;

    {
        const int n = t & 31;
        const int kbase = (t >> 5) * CHUNK;
        int row = n0 + n;
        if (row >= N_) row = N_ - 1;
        const InT* xr = X + (size_t)row * H_DIM;
#pragma unroll
        for (int jj = 0; jj < CHUNK / 4; ++jj) {
            int k = kbase + jj * 4;
            float4 v = ld4(xr + k);
            if constexpr (BN) {
                float4 a = *(const float4*)(Abn + k);
                float4 b = *(const float4*)(Bbn + k);
                v.x = fmaxf(fmaf(v.x, a.x, b.x), 0.f);
                v.y = fmaxf(fmaf(v.y, a.y, b.y), 0.f);
                v.z = fmaxf(fmaf(v.z, a.z, b.z), 0.f);
                v.w = fmaxf(fmaf(v.w, a.w, b.w), 0.f);
            }
            XT[k + 0][n] = v.x;
            XT[k + 1][n] = v.y;
            XT[k + 2][n] = v.z;
            XT[k + 3][n] = v.w;
        }
    }
    __syncthreads();

    const int cg = t >> 3;
    const int m  = t & 7;
    if ((4 * cg) < WCOLS) {
        float acc[4][4];
#pragma unroll
        for (int i = 0; i < 4; ++i)
#pragma unroll
            for (int j = 0; j < 4; ++j) acc[i][j] = 0.f;

        const float* Wp = W + 4 * cg;
#pragma unroll 4
        for (int k = 0; k < H_DIM; ++k) {
            float4 xv = *(const float4*)&XT[k][4 * m];
            float4 wv = *(const float4*)(Wp + (size_t)k * WCOLS);
            acc[0][0] = fmaf(xv.x, wv.x, acc[0][0]);
            acc[0][1] = fmaf(xv.x, wv.y, acc[0][1]);
            acc[0][2] = fmaf(xv.x, wv.z, acc[0][2]);
            acc[0][3] = fmaf(xv.x, wv.w, acc[0][3]);
            acc[1][0] = fmaf(xv.y, wv.x, acc[1][0]);
            acc[1][1] = fmaf(xv.y, wv.y, acc[1][1]);
            acc[1][2] = fmaf(xv.y, wv.z, acc[1][2]);
            acc[1][3] = fmaf(xv.y, wv.w, acc[1][3]);
            acc[2][0] = fmaf(xv.z, wv.x, acc[2][0]);
            acc[2][1] = fmaf(xv.z, wv.y, acc[2][1]);
            acc[2][2] = fmaf(xv.z, wv.z, acc[2][2]);
            acc[2][3] = fmaf(xv.z, wv.w, acc[2][3]);
            acc[3][0] = fmaf(xv.w, wv.x, acc[3][0]);
            acc[3][1] = fmaf(xv.w, wv.y, acc[3][1]);
            acc[3][2] = fmaf(xv.w, wv.z, acc[3][2]);
            acc[3][3] = fmaf(xv.w, wv.w, acc[3][3]);
        }

        float4 bv = make_float4(0.f, 0.f, 0.f, 0.f);
        if (bias) {
            bv.x = bias[4 * cg + 0]; bv.y = bias[4 * cg + 1];
            bv.z = bias[4 * cg + 2]; bv.w = bias[4 * cg + 3];
        }
#pragma unroll
        for (int i = 0; i < 4; ++i) {
            int row = n0 + 4 * m + i;
            if (row < N_) {
                float4 o;
                o.x = acc[i][0] + bv.x;
                o.y = acc[i][1] + bv.y;
                o.z = acc[i][2] + bv.z;
                o.w = acc[i][3] + bv.w;
                st4(Y + (size_t)row * ldY + 4 * cg, o);
            }
        }
    }
}

// ---------------- aggregation: out[d] = dinv[d]*(g[d] + sum g[src_e]) + bias ----------------
// one wave per node, half2 per lane; 8 independent gathers in flight
__global__ __launch_bounds__(256) void aggregate_kernel(
    const __half2* __restrict__ Gp,           // [N][64] half2 (dinv-scaled h)
    const int* __restrict__ rowptr,
    const int* __restrict__ cols,
    const float* __restrict__ dinv, const float* __restrict__ bias,
    __half2* __restrict__ out, int N_)
{
    int wave = threadIdx.x >> 6;
    int lane = threadIdx.x & 63;
    int n = blockIdx.x * 4 + wave;
    if (n >= N_) return;

    float2 self = __half22float2(Gp[(size_t)n * 64 + lane]);
    float s0[8], s1[8];
    s0[0] = self.x; s1[0] = self.y;
#pragma unroll
    for (int u = 1; u < 8; ++u) { s0[u] = 0.f; s1[u] = 0.f; }

    int e = rowptr[n];
    const int e1 = rowptr[n + 1];
    for (; e + 7 < e1; e += 8) {
        int sc[8];
#pragma unroll
        for (int u = 0; u < 8; ++u) sc[u] = cols[e + u];
#pragma unroll
        for (int u = 0; u < 8; ++u) {
            float2 h = __half22float2(Gp[(size_t)sc[u] * 64 + lane]);
            s0[u] += h.x; s1[u] += h.y;
        }
    }
    for (; e < e1; ++e) {
        float2 h = __half22float2(Gp[(size_t)cols[e] * 64 + lane]);
        s0[0] += h.x; s1[0] += h.y;
    }
    float t0 = ((s0[0] + s0[1]) + (s0[2] + s0[3])) + ((s0[4] + s0[5]) + (s0[6] + s0[7]));
    float t1 = ((s1[0] + s1[1]) + (s1[2] + s1[3])) + ((s1[4] + s1[5]) + (s1[6] + s1[7]));
    float di = dinv[n];
    int c = lane * 2;
    float o0 = fmaf(di, t0, bias[c]);
    float o1 = fmaf(di, t1, bias[c + 1]);
    out[(size_t)n * 64 + lane] = __floats2half2_rn(o0, o1);
}

// ---------------- BN stats: wave streams full rows, register accum, block combine ----------------
__global__ __launch_bounds__(256) void bn_stats_kernel(
    const __half2* __restrict__ X, float* __restrict__ gsum, float* __restrict__ gsq,
    int N_, int stride)
{
    __shared__ float ssum[4][128], ssq[4][128];
    const int wave = threadIdx.x >> 6;
    const int lane = threadIdx.x & 63;
    float r0 = 0.f, r1 = 0.f, q0 = 0.f, q1 = 0.f;
    for (int n = blockIdx.x * 4 + wave; n < N_; n += stride) {
        float2 v = __half22float2(X[(size_t)n * 64 + lane]);
        r0 += v.x; r1 += v.y;
        q0 = fmaf(v.x, v.x, q0); q1 = fmaf(v.y, v.y, q1);
    }
    int c = lane * 2;
    ssum[wave][c] = r0; ssum[wave][c + 1] = r1;
    ssq[wave][c]  = q0; ssq[wave][c + 1]  = q1;
    __syncthreads();
    if (threadIdx.x < 128) {
        int k = threadIdx.x;
        float s = (ssum[0][k] + ssum[1][k]) + (ssum[2][k] + ssum[3][k]);
        float q = (ssq[0][k] + ssq[1][k]) + (ssq[2][k] + ssq[3][k]);
        atomicAdd(&gsum[k], s);
        atomicAdd(&gsq[k], q);
    }
}

__global__ __launch_bounds__(128) void bn_finalize_kernel(
    const float* __restrict__ sum, const float* __restrict__ sumsq,
    const float* __restrict__ gamma, const float* __restrict__ beta,
    float* __restrict__ A, float* __restrict__ B, int N_)
{
    int c = threadIdx.x;
    float inv_n = 1.0f / (float)N_;
    float mean = sum[c] * inv_n;
    float var = sumsq[c] * inv_n - mean * mean;
    float rstd = rsqrtf(var + 1e-5f);
    float a = rstd * gamma[c];
    A[c] = a;
    B[c] = beta[c] - mean * a;
}

// ---------------- launch ----------------
extern "C" void kernel_launch(void* const* d_in, const int* in_sizes, int n_in,
                              void* d_out, int out_size, void* d_ws, size_t ws_size,
                              hipStream_t stream) {
    const float* x   = (const float*)d_in[0];
    const int* esrc  = (const int*)d_in[1];
    const int* edst  = (const int*)d_in[2];
    const float* W1  = (const float*)d_in[3];
    const float* b1  = (const float*)d_in[4];
    const float* g1  = (const float*)d_in[5];
    const float* bt1 = (const float*)d_in[6];
    const float* W2  = (const float*)d_in[7];
    const float* b2  = (const float*)d_in[8];
    const float* g2  = (const float*)d_in[9];
    const float* bt2 = (const float*)d_in[10];
    const float* Wr  = (const float*)d_in[11];
    const float* br  = (const float*)d_in[12];

    const int N_ = in_sizes[0] / H_DIM;     // 100000
    const int E_ = in_sizes[1];             // 1600000
    const int OUTC = out_size / N_;         // 40

    char* p = (char*)d_ws;
    auto alloc = [&](size_t bytes) -> void* {
        void* r = (void*)p;
        p += (bytes + 255) & ~(size_t)255;
        return r;
    };
    __half* tmpA = (__half*)alloc((size_t)N_ * H_DIM * 2);
    __half* tmpB = (__half*)alloc((size_t)N_ * H_DIM * 2);
    int*   cols  = (int*)  alloc((size_t)E_ * 4);
    int*   rowptr= (int*)  alloc((size_t)(N_ + 1) * 4);
    int*   degcur= (int*)  alloc((size_t)2 * N_ * 4);
    int*   deg   = degcur;
    int*   cursor= degcur + N_;
    float* dinv  = (float*)alloc((size_t)N_ * 4);
    int*   bsum  = (int*)  alloc(4096);
    int*   boff  = (int*)  alloc(4096);
    float* bnbuf = (float*)alloc(8 * 128 * 4);
    float* sum1 = bnbuf,       *sq1 = bnbuf + 128;
    float* sum2 = bnbuf + 256, *sq2 = bnbuf + 384;
    float* A1 = bnbuf + 512, *B1 = bnbuf + 640;
    float* A2 = bnbuf + 768, *B2 = bnbuf + 896;

    hipMemsetAsync(degcur, 0, (size_t)2 * N_ * 4, stream);
    hipMemsetAsync(bnbuf, 0, 4 * 128 * 4, stream);

    const int nb = (N_ + 255) / 256;
    const int eb = (E_ + 255) / 256;
    const int ntiles32 = (N_ + 31) / 32;
    const int ntiles64 = (N_ + 63) / 64;

    int shift = 0;                           // buckets (d>>shift) in 0..7
    while (((N_ - 1) >> shift) > 7) ++shift; // N=100000 -> shift=14, buckets 0..6

    const int BN_BLOCKS = 1024;
    const int BN_STRIDE = BN_BLOCKS * 4;

    degree_kernel<<<eb, 256, 0, stream>>>(edst, deg, E_);
    dinv_kernel<<<nb, 256, 0, stream>>>(deg, dinv, N_);
    scan_block_kernel<<<nb, 256, 0, stream>>>(deg, rowptr, bsum, N_);
    scan_bsums_kernel<<<1, 512, 0, stream>>>(bsum, boff, nb);
    scan_add_kernel<<<nb, 256, 0, stream>>>(rowptr, boff, N_, E_);
    csr_fill_kernel<<<eb * 8, 256, 0, stream>>>(esrc, edst, rowptr, cursor, cols, E_, N_, shift);

    // layer 1: g1 = dinv .* (x @ W1)   (f32 in, fp16 out, MFMA)
    gemm_mfma_kernel<false, float><<<ntiles64, 256, 0, stream>>>(
        x, W1, nullptr, nullptr, dinv, (_Float16*)tmpA, N_);
    aggregate_kernel<<<(N_ + 3) / 4, 256, 0, stream>>>(
        (const __half2*)tmpA, rowptr, cols, dinv, b1, (__half2*)tmpB, N_);
    bn_stats_kernel<<<BN_BLOCKS, 256, 0, stream>>>(
        (const __half2*)tmpB, sum1, sq1, N_, BN_STRIDE);
    bn_finalize_kernel<<<1, 128, 0, stream>>>(sum1, sq1, g1, bt1, A1, B1, N_);

    // layer 2: g2 = dinv .* (bnrelu(h1) @ W2)   (fp16 in/out, MFMA, BN fused)
    gemm_mfma_kernel<true, _Float16><<<ntiles64, 256, 0, stream>>>(
        (const _Float16*)tmpB, W2, A1, B1, dinv, (_Float16*)tmpA, N_);
    aggregate_kernel<<<(N_ + 3) / 4, 256, 0, stream>>>(
        (const __half2*)tmpA, rowptr, cols, dinv, b2, (__half2*)tmpB, N_);
    bn_stats_kernel<<<BN_BLOCKS, 256, 0, stream>>>(
        (const __half2*)tmpB, sum2, sq2, N_, BN_STRIDE);
    bn_finalize_kernel<<<1, 128, 0, stream>>>(sum2, sq2, g2, bt2, A2, B2, N_);

    // readout (VALU, BN+bias fused, f32 out)
    gemm_kernel<64, true, __half, float><<<ntiles32, 128, 0, stream>>>(
        tmpB, Wr, A2, B2, br, (float*)d_out, N_, OUTC, OUTC);
}

// Round 6
// 554.559 us; speedup vs baseline: 1.5451x; 1.0324x over previous
//
#include <hip/hip_runtime.h>
#include <hip/hip_bf16.h>
#include <hip/hip_fp16.h>

#define H_DIM 128

typedef _Float16 half8 __attribute__((ext_vector_type(8)));
typedef float floatx4 __attribute__((ext_vector_type(4)));

// ---------------- degree ----------------
__global__ void degree_kernel(const int* __restrict__ dst, int* __restrict__ deg, int E_) {
    int i = blockIdx.x * blockDim.x + threadIdx.x;
    if (i < E_) atomicAdd(&deg[dst[i]], 1);
}

// ---------------- exclusive scan (3-kernel), dinv fused into pass 1 ----------------
__global__ void scan_block_kernel(const int* __restrict__ deg, float* __restrict__ dinv,
                                  int* __restrict__ rowptr, int* __restrict__ bsum, int N_) {
    __shared__ int sh[256];
    int i = blockIdx.x * 256 + threadIdx.x;
    int v = (i < N_) ? deg[i] : 0;
    if (i < N_) dinv[i] = rsqrtf((float)v + 1.0f);
    sh[threadIdx.x] = v;
    __syncthreads();
    for (int off = 1; off < 256; off <<= 1) {
        int t = (threadIdx.x >= off) ? sh[threadIdx.x - off] : 0;
        __syncthreads();
        sh[threadIdx.x] += t;
        __syncthreads();
    }
    if (i < N_) rowptr[i] = sh[threadIdx.x] - v;   // exclusive
    if (threadIdx.x == 255) bsum[blockIdx.x] = sh[255];
}

__global__ void scan_bsums_kernel(const int* __restrict__ bsum, int* __restrict__ boff, int nb) {
    __shared__ int sh[512];
    int v = (threadIdx.x < nb) ? bsum[threadIdx.x] : 0;
    sh[threadIdx.x] = v;
    __syncthreads();
    for (int off = 1; off < 512; off <<= 1) {
        int t = (threadIdx.x >= off) ? sh[threadIdx.x - off] : 0;
        __syncthreads();
        sh[threadIdx.x] += t;
        __syncthreads();
    }
    if (threadIdx.x < nb) boff[threadIdx.x] = sh[threadIdx.x] - v;  // exclusive
}

__global__ void scan_add_kernel(int* __restrict__ rowptr, const int* __restrict__ boff,
                                int N_, int E_) {
    int i = blockIdx.x * 256 + threadIdx.x;
    if (i < N_) rowptr[i] += boff[blockIdx.x];
    if (i == 0) rowptr[N_] = E_;
}

// ---------------- CSR fill, XCD-binned by dst bucket ----------------
__global__ void csr_fill_kernel(const int* __restrict__ src, const int* __restrict__ dst,
                                const int* __restrict__ rowptr, int* __restrict__ cursor,
                                int* __restrict__ cols, int E_, int N_, int shift) {
    int b = blockIdx.x & 7;
    if (((N_ - 1) >> shift) < b) return;          // bucket never occurs
    int i = (blockIdx.x >> 3) * blockDim.x + threadIdx.x;
    if (i < E_) {
        int d = dst[i];
        if ((d >> shift) == b) {
            int p = rowptr[d] + atomicAdd(&cursor[d], 1);
            cols[p] = src[i];
        }
    }
}

// ---------------- MFMA fragment helpers ----------------
__device__ inline half8 a_frag_f32(const float* Xr, int k0) {
    float4 v0 = *(const float4*)(Xr + k0);
    float4 v1 = *(const float4*)(Xr + k0 + 4);
    half8 a;
    a[0] = (_Float16)v0.x; a[1] = (_Float16)v0.y; a[2] = (_Float16)v0.z; a[3] = (_Float16)v0.w;
    a[4] = (_Float16)v1.x; a[5] = (_Float16)v1.y; a[6] = (_Float16)v1.z; a[7] = (_Float16)v1.w;
    return a;
}
__device__ inline half8 a_frag_f16_bn(const _Float16* Xr, int k0,
                                      const float* __restrict__ A, const float* __restrict__ B) {
    half8 r = *(const half8*)(Xr + k0);
    float4 a0 = *(const float4*)(A + k0);
    float4 a1 = *(const float4*)(A + k0 + 4);
    float4 b0 = *(const float4*)(B + k0);
    float4 b1 = *(const float4*)(B + k0 + 4);
    half8 o;
    o[0] = (_Float16)fmaxf(fmaf((float)r[0], a0.x, b0.x), 0.f);
    o[1] = (_Float16)fmaxf(fmaf((float)r[1], a0.y, b0.y), 0.f);
    o[2] = (_Float16)fmaxf(fmaf((float)r[2], a0.z, b0.z), 0.f);
    o[3] = (_Float16)fmaxf(fmaf((float)r[3], a0.w, b0.w), 0.f);
    o[4] = (_Float16)fmaxf(fmaf((float)r[4], a1.x, b1.x), 0.f);
    o[5] = (_Float16)fmaxf(fmaf((float)r[5], a1.y, b1.y), 0.f);
    o[6] = (_Float16)fmaxf(fmaf((float)r[6], a1.z, b1.z), 0.f);
    o[7] = (_Float16)fmaxf(fmaf((float)r[7], a1.w, b1.w), 0.f);
    return o;
}

// ---------------- MFMA GEMM: Y[N,128] = dinv .* (bnrelu(X)[N,128] @ W[128,128]) ----------------
template<bool BN, typename InT>
__global__ __launch_bounds__(256) void gemm_mfma_kernel(
    const InT* __restrict__ X, const float* __restrict__ W,
    const float* __restrict__ Abn, const float* __restrict__ Bbn,
    const float* __restrict__ dinv,
    _Float16* __restrict__ Y, int N_)
{
    __shared__ _Float16 Wf[32 * 64 * 8];   // 32 KB: [nt*4+kb][lane][j]

    const int tid = threadIdx.x;
    for (int idx = tid; idx < 128 * 32; idx += 256) {
        int k = idx >> 5;                   // 0..127
        int n0 = (idx & 31) * 4;
        float4 w = *(const float4*)(W + k * 128 + n0);
        int kb = k >> 5, q = (k >> 3) & 3, j = k & 7;
#pragma unroll
        for (int u = 0; u < 4; ++u) {
            int n = n0 + u;
            int lane = (n & 15) | (q << 4);
            Wf[((((n >> 4) * 4 + kb) * 64 + lane) << 3) + j] = (_Float16)((&w.x)[u]);
        }
    }
    __syncthreads();

    const int wv = tid >> 6, lane = tid & 63;
    const int m = lane & 15, q = lane >> 4;
    const int row0 = blockIdx.x * 64 + wv * 16;

    int arow = row0 + m;
    if (arow >= N_) arow = N_ - 1;
    const InT* Xr = X + (size_t)arow * H_DIM;

    half8 a[4];
#pragma unroll
    for (int kb = 0; kb < 4; ++kb) {
        int k0 = kb * 32 + q * 8;
        if constexpr (BN) a[kb] = a_frag_f16_bn((const _Float16*)Xr, k0, Abn, Bbn);
        else              a[kb] = a_frag_f32((const float*)Xr, k0);
    }

    floatx4 acc[8];
#pragma unroll
    for (int nt = 0; nt < 8; ++nt) acc[nt] = (floatx4){0.f, 0.f, 0.f, 0.f};

#pragma unroll
    for (int nt = 0; nt < 8; ++nt) {
#pragma unroll
        for (int kb = 0; kb < 4; ++kb) {
            half8 b = *(const half8*)&Wf[(((nt * 4 + kb) * 64 + lane) << 3)];
            acc[nt] = __builtin_amdgcn_mfma_f32_16x16x32_f16(a[kb], b, acc[nt], 0, 0, 0);
        }
    }

#pragma unroll
    for (int r = 0; r < 4; ++r) {
        int row = row0 + q * 4 + r;
        if (row < N_) {
            float ds = dinv[row];
            _Float16* Yr = Y + (size_t)row * H_DIM + m;
#pragma unroll
            for (int nt = 0; nt < 8; ++nt)
                Yr[nt * 16] = (_Float16)(ds * acc[nt][r]);
        }
    }
}

// ---------------- MFMA readout: Y[N,40] = bnrelu(X)[N,128] @ Wr[128,40] + br ----------------
__global__ __launch_bounds__(256) void readout_mfma_kernel(
    const _Float16* __restrict__ X, const float* __restrict__ W,   // [128, OUTC]
    const float* __restrict__ Abn, const float* __restrict__ Bbn,
    const float* __restrict__ br,
    float* __restrict__ Y, int N_, int OUTC)
{
    __shared__ _Float16 Wf[12 * 64 * 8];   // 12 KB: 3 n-tiles (48 cols padded)

    const int tid = threadIdx.x;
    for (int idx = tid; idx < 128 * 64; idx += 256) {
        int k = idx >> 6, n = idx & 63;
        if (n < 48) {
            float w = (n < OUTC) ? W[k * OUTC + n] : 0.f;
            int kb = k >> 5, q = (k >> 3) & 3, j = k & 7;
            int lane = (n & 15) | (q << 4);
            Wf[((((n >> 4) * 4 + kb) * 64 + lane) << 3) + j] = (_Float16)w;
        }
    }
    __syncthreads();

    const int wv = tid >> 6, lane = tid & 63;
    const int m = lane & 15, q = lane >> 4;
    const int row0 = blockIdx.x * 64 + wv * 16;

    int arow = row0 + m;
    if (arow >= N_) arow = N_ - 1;
    const _Float16* Xr = X + (size_t)arow * H_DIM;

    half8 a[4];
#pragma unroll
    for (int kb = 0; kb < 4; ++kb)
        a[kb] = a_frag_f16_bn(Xr, kb * 32 + q * 8, Abn, Bbn);

    floatx4 acc[3];
#pragma unroll
    for (int nt = 0; nt < 3; ++nt) acc[nt] = (floatx4){0.f, 0.f, 0.f, 0.f};

#pragma unroll
    for (int nt = 0; nt < 3; ++nt) {
#pragma unroll
        for (int kb = 0; kb < 4; ++kb) {
            half8 b = *(const half8*)&Wf[(((nt * 4 + kb) * 64 + lane) << 3)];
            acc[nt] = __builtin_amdgcn_mfma_f32_16x16x32_f16(a[kb], b, acc[nt], 0, 0, 0);
        }
    }

#pragma unroll
    for (int nt = 0; nt < 3; ++nt) {
        int col = nt * 16 + m;
        if (col < OUTC) {
            float bb = br[col];
#pragma unroll
            for (int r = 0; r < 4; ++r) {
                int row = row0 + q * 4 + r;
                if (row < N_)
                    Y[(size_t)row * OUTC + col] = acc[nt][r] + bb;
            }
        }
    }
}

// ---------------- aggregation: out[d] = dinv[d]*(g[d] + sum g[src_e]) + bias ----------------
// one wave per node, half2/lane, packed fp16 accumulation (8-way split => short chains)
__global__ __launch_bounds__(256) void aggregate_kernel(
    const __half2* __restrict__ Gp,           // [N][64] half2 (dinv-scaled h)
    const int* __restrict__ rowptr,
    const int* __restrict__ cols,
    const float* __restrict__ dinv, const float* __restrict__ bias,
    __half2* __restrict__ out, int N_)
{
    int wave = threadIdx.x >> 6;
    int lane = threadIdx.x & 63;
    int n = blockIdx.x * 4 + wave;
    if (n >= N_) return;

    const __half2 z = __float2half2_rn(0.f);
    __half2 acc[8];
    acc[0] = Gp[(size_t)n * 64 + lane];       // self term
#pragma unroll
    for (int u = 1; u < 8; ++u) acc[u] = z;

    int e = rowptr[n];
    const int e1 = rowptr[n + 1];
    for (; e + 7 < e1; e += 8) {
        __half2 h[8];
#pragma unroll
        for (int u = 0; u < 8; ++u) h[u] = Gp[(size_t)cols[e + u] * 64 + lane];
#pragma unroll
        for (int u = 0; u < 8; ++u) acc[u] = __hadd2(acc[u], h[u]);
    }
    for (; e < e1; ++e)
        acc[0] = __hadd2(acc[0], Gp[(size_t)cols[e] * 64 + lane]);

    // pairwise fp16 tree, final sum in fp32
    __half2 p0 = __hadd2(__hadd2(acc[0], acc[1]), __hadd2(acc[2], acc[3]));
    __half2 p1 = __hadd2(__hadd2(acc[4], acc[5]), __hadd2(acc[6], acc[7]));
    float2 f0 = __half22float2(p0);
    float2 f1 = __half22float2(p1);
    float di = dinv[n];
    int c = lane * 2;
    float o0 = fmaf(di, f0.x + f1.x, bias[c]);
    float o1 = fmaf(di, f0.y + f1.y, bias[c + 1]);
    out[(size_t)n * 64 + lane] = __floats2half2_rn(o0, o1);
}

// ---------------- BN stats: wave streams full rows, register accum, block combine ----------------
__global__ __launch_bounds__(256) void bn_stats_kernel(
    const __half2* __restrict__ X, float* __restrict__ gsum, float* __restrict__ gsq,
    int N_, int stride)
{
    __shared__ float ssum[4][128], ssq[4][128];
    const int wave = threadIdx.x >> 6;
    const int lane = threadIdx.x & 63;
    float r0 = 0.f, r1 = 0.f, q0 = 0.f, q1 = 0.f;
    for (int n = blockIdx.x * 4 + wave; n < N_; n += stride) {
        float2 v = __half22float2(X[(size_t)n * 64 + lane]);
        r0 += v.x; r1 += v.y;
        q0 = fmaf(v.x, v.x, q0); q1 = fmaf(v.y, v.y, q1);
    }
    int c = lane * 2;
    ssum[wave][c] = r0; ssum[wave][c + 1] = r1;
    ssq[wave][c]  = q0; ssq[wave][c + 1]  = q1;
    __syncthreads();
    if (threadIdx.x < 128) {
        int k = threadIdx.x;
        float s = (ssum[0][k] + ssum[1][k]) + (ssum[2][k] + ssum[3][k]);
        float q = (ssq[0][k] + ssq[1][k]) + (ssq[2][k] + ssq[3][k]);
        atomicAdd(&gsum[k], s);
        atomicAdd(&gsq[k], q);
    }
}

__global__ __launch_bounds__(128) void bn_finalize_kernel(
    const float* __restrict__ sum, const float* __restrict__ sumsq,
    const float* __restrict__ gamma, const float* __restrict__ beta,
    float* __restrict__ A, float* __restrict__ B, int N_)
{
    int c = threadIdx.x;
    float inv_n = 1.0f / (float)N_;
    float mean = sum[c] * inv_n;
    float var = sumsq[c] * inv_n - mean * mean;
    float rstd = rsqrtf(var + 1e-5f);
    float a = rstd * gamma[c];
    A[c] = a;
    B[c] = beta[c] - mean * a;
}

// ---------------- launch ----------------
extern "C" void kernel_launch(void* const* d_in, const int* in_sizes, int n_in,
                              void* d_out, int out_size, void* d_ws, size_t ws_size,
                              hipStream_t stream) {
    const float* x   = (const float*)d_in[0];
    const int* esrc  = (const int*)d_in[1];
    const int* edst  = (const int*)d_in[2];
    const float* W1  = (const float*)d_in[3];
    const float* b1  = (const float*)d_in[4];
    const float* g1  = (const float*)d_in[5];
    const float* bt1 = (const float*)d_in[6];
    const float* W2  = (const float*)d_in[7];
    const float* b2  = (const float*)d_in[8];
    const float* g2  = (const float*)d_in[9];
    const float* bt2 = (const float*)d_in[10];
    const float* Wr  = (const float*)d_in[11];
    const float* br  = (const float*)d_in[12];

    const int N_ = in_sizes[0] / H_DIM;     // 100000
    const int E_ = in_sizes[1];             // 1600000
    const int OUTC = out_size / N_;         // 40

    char* p = (char*)d_ws;
    auto alloc = [&](size_t bytes) -> void* {
        void* r = (void*)p;
        p += (bytes + 255) & ~(size_t)255;
        return r;
    };
    __half* tmpA = (__half*)alloc((size_t)N_ * H_DIM * 2);
    __half* tmpB = (__half*)alloc((size_t)N_ * H_DIM * 2);
    int*   cols  = (int*)  alloc((size_t)E_ * 4);
    int*   rowptr= (int*)  alloc((size_t)(N_ + 1) * 4);
    // zero-region: degcur (2N ints) + bn sums (512 floats) contiguous, single memset
    size_t degcur_sz = ((size_t)2 * N_ * 4 + 255) & ~(size_t)255;
    int*   degcur= (int*)  alloc((size_t)2 * N_ * 4);
    float* bnbuf = (float*)alloc(8 * 128 * 4);
    int*   deg   = degcur;
    int*   cursor= degcur + N_;
    float* sum1 = bnbuf,       *sq1 = bnbuf + 128;
    float* sum2 = bnbuf + 256, *sq2 = bnbuf + 384;
    float* A1 = bnbuf + 512, *B1 = bnbuf + 640;
    float* A2 = bnbuf + 768, *B2 = bnbuf + 896;
    float* dinv  = (float*)alloc((size_t)N_ * 4);
    int*   bsum  = (int*)  alloc(4096);
    int*   boff  = (int*)  alloc(4096);

    hipMemsetAsync(degcur, 0, degcur_sz + 4 * 128 * 4, stream);  // deg+cursor+sum1/sq1/sum2/sq2

    const int nb = (N_ + 255) / 256;
    const int eb = (E_ + 255) / 256;
    const int ntiles64 = (N_ + 63) / 64;

    int shift = 0;                           // buckets (d>>shift) in 0..7
    while (((N_ - 1) >> shift) > 7) ++shift; // N=100000 -> shift=14, buckets 0..6

    const int BN_BLOCKS = 1024;
    const int BN_STRIDE = BN_BLOCKS * 4;

    degree_kernel<<<eb, 256, 0, stream>>>(edst, deg, E_);
    scan_block_kernel<<<nb, 256, 0, stream>>>(deg, dinv, rowptr, bsum, N_);
    scan_bsums_kernel<<<1, 512, 0, stream>>>(bsum, boff, nb);
    scan_add_kernel<<<nb, 256, 0, stream>>>(rowptr, boff, N_, E_);
    csr_fill_kernel<<<eb * 8, 256, 0, stream>>>(esrc, edst, rowptr, cursor, cols, E_, N_, shift);

    // layer 1: g1 = dinv .* (x @ W1)   (f32 in, fp16 out, MFMA)
    gemm_mfma_kernel<false, float><<<ntiles64, 256, 0, stream>>>(
        x, W1, nullptr, nullptr, dinv, (_Float16*)tmpA, N_);
    aggregate_kernel<<<(N_ + 3) / 4, 256, 0, stream>>>(
        (const __half2*)tmpA, rowptr, cols, dinv, b1, (__half2*)tmpB, N_);
    bn_stats_kernel<<<BN_BLOCKS, 256, 0, stream>>>(
        (const __half2*)tmpB, sum1, sq1, N_, BN_STRIDE);
    bn_finalize_kernel<<<1, 128, 0, stream>>>(sum1, sq1, g1, bt1, A1, B1, N_);

    // layer 2: g2 = dinv .* (bnrelu(h1) @ W2)   (fp16 in/out, MFMA, BN fused)
    gemm_mfma_kernel<true, _Float16><<<ntiles64, 256, 0, stream>>>(
        (const _Float16*)tmpB, W2, A1, B1, dinv, (_Float16*)tmpA, N_);
    aggregate_kernel<<<(N_ + 3) / 4, 256, 0, stream>>>(
        (const __half2*)tmpA, rowptr, cols, dinv, b2, (__half2*)tmpB, N_);
    bn_stats_kernel<<<BN_BLOCKS, 256, 0, stream>>>(
        (const __half2*)tmpB, sum2, sq2, N_, BN_STRIDE);
    bn_finalize_kernel<<<1, 128, 0, stream>>>(sum2, sq2, g2, bt2, A2, B2, N_);

    // readout (MFMA, BN+bias fused, f32 out)
    readout_mfma_kernel<<<ntiles64, 256, 0, stream>>>(
        (const _Float16*)tmpB, Wr, A2, B2, br, (float*)d_out, N_, OUTC);
}